// Round 4
// baseline (335.433 us; speedup 1.0000x reference)
//
#include <hip/hip_runtime.h>
#include <math.h>

typedef unsigned short u16;
typedef __bf16 bf16x8 __attribute__((ext_vector_type(8)));
typedef float f32x4 __attribute__((ext_vector_type(4)));
typedef unsigned short u16x8 __attribute__((ext_vector_type(8)));

static __device__ __forceinline__ u16 f2bf(float f) {
  unsigned int u = __builtin_bit_cast(unsigned int, f);
  u = (u + 0x7FFFu + ((u >> 16) & 1u)) >> 16;
  return (u16)u;
}
static __device__ __forceinline__ float bf2f(u16 u) {
  unsigned int x = ((unsigned int)u) << 16;
  return __builtin_bit_cast(float, x);
}

// ---------------- f32 -> (hi, lo) bf16 split ----------------
__global__ __launch_bounds__(256) void cvt_split(const float* __restrict__ src, u16* __restrict__ hi,
                                                 u16* __restrict__ lo, int n4) {
  int idx = blockIdx.x * 256 + threadIdx.x;
  if (idx < n4) {
    float4 v = ((const float4*)src)[idx];
    ushort4 h, l;
    h.x = f2bf(v.x); l.x = f2bf(v.x - bf2f(h.x));
    h.y = f2bf(v.y); l.y = f2bf(v.y - bf2f(h.y));
    h.z = f2bf(v.z); l.z = f2bf(v.z - bf2f(h.z));
    h.w = f2bf(v.w); l.w = f2bf(v.w - bf2f(h.w));
    ((ushort4*)hi)[idx] = h;
    ((ushort4*)lo)[idx] = l;
  }
}

// ---------------- plain bf16 NT GEMM: C = A * B^T, f32 out ----------------
// 128x128 tile, BK=32, 256 threads (4 waves, each 64x64).
__global__ __launch_bounds__(256) void gemm_nt(const u16* __restrict__ A, const u16* __restrict__ B,
                                               float* __restrict__ C, int M, int N, int K) {
  __shared__ __align__(16) u16 sA[128][40];
  __shared__ __align__(16) u16 sB[128][40];
  const int tid = threadIdx.x;
  const int w = tid >> 6, lane = tid & 63;
  const int m0 = blockIdx.x * 128, n0 = blockIdx.y * 128;
  const int wm = (w >> 1) * 64, wn = (w & 1) * 64;

  f32x4 acc[4][4] = {};
  const int srw = tid >> 1, sc0 = (tid & 1) * 16;

  for (int k0 = 0; k0 < K; k0 += 32) {
    {
      const u16* pa = A + (size_t)(m0 + srw) * K + k0 + sc0;
      const u16* pb = B + (size_t)(n0 + srw) * K + k0 + sc0;
      *(u16x8*)&sA[srw][sc0]     = *(const u16x8*)pa;
      *(u16x8*)&sA[srw][sc0 + 8] = *(const u16x8*)(pa + 8);
      *(u16x8*)&sB[srw][sc0]     = *(const u16x8*)pb;
      *(u16x8*)&sB[srw][sc0 + 8] = *(const u16x8*)(pb + 8);
    }
    __syncthreads();
    bf16x8 af[4], bfr[4];
#pragma unroll
    for (int m = 0; m < 4; ++m) af[m] = *(const bf16x8*)&sA[wm + m * 16 + (lane & 15)][(lane >> 4) * 8];
#pragma unroll
    for (int n = 0; n < 4; ++n) bfr[n] = *(const bf16x8*)&sB[wn + n * 16 + (lane & 15)][(lane >> 4) * 8];
#pragma unroll
    for (int m = 0; m < 4; ++m)
#pragma unroll
      for (int n = 0; n < 4; ++n)
        acc[m][n] = __builtin_amdgcn_mfma_f32_16x16x32_bf16(af[m], bfr[n], acc[m][n], 0, 0, 0);
    __syncthreads();
  }

#pragma unroll
  for (int m = 0; m < 4; ++m)
#pragma unroll
    for (int i = 0; i < 4; ++i) {
      int gr = m0 + wm + m * 16 + (lane >> 4) * 4 + i;
      float* crow = C + (size_t)gr * N + n0 + wn + (lane & 15);
#pragma unroll
      for (int n = 0; n < 4; ++n) crow[n * 16] = acc[m][n][i];
    }
}

// ---------------- split-bf16 NT GEMM (3-term) for the output projection ----------------
__global__ __launch_bounds__(256) void gemm_split(const u16* __restrict__ Ah, const u16* __restrict__ Al,
                                                  const u16* __restrict__ Bh, const u16* __restrict__ Bl,
                                                  float* __restrict__ C, int M, int N, int K) {
  __shared__ __align__(16) u16 sAh[128][40];
  __shared__ __align__(16) u16 sAl[128][40];
  __shared__ __align__(16) u16 sBh[128][40];
  __shared__ __align__(16) u16 sBl[128][40];
  const int tid = threadIdx.x;
  const int w = tid >> 6, lane = tid & 63;
  const int m0 = blockIdx.x * 128, n0 = blockIdx.y * 128;
  const int wm = (w >> 1) * 64, wn = (w & 1) * 64;

  f32x4 acc[4][4] = {};
  const int srw = tid >> 1, sc0 = (tid & 1) * 16;

  for (int k0 = 0; k0 < K; k0 += 32) {
    {
      const u16* pa  = Ah + (size_t)(m0 + srw) * K + k0 + sc0;
      const u16* pal = Al + (size_t)(m0 + srw) * K + k0 + sc0;
      const u16* pb  = Bh + (size_t)(n0 + srw) * K + k0 + sc0;
      const u16* pbl = Bl + (size_t)(n0 + srw) * K + k0 + sc0;
      *(u16x8*)&sAh[srw][sc0]     = *(const u16x8*)pa;
      *(u16x8*)&sAh[srw][sc0 + 8] = *(const u16x8*)(pa + 8);
      *(u16x8*)&sAl[srw][sc0]     = *(const u16x8*)pal;
      *(u16x8*)&sAl[srw][sc0 + 8] = *(const u16x8*)(pal + 8);
      *(u16x8*)&sBh[srw][sc0]     = *(const u16x8*)pb;
      *(u16x8*)&sBh[srw][sc0 + 8] = *(const u16x8*)(pb + 8);
      *(u16x8*)&sBl[srw][sc0]     = *(const u16x8*)pbl;
      *(u16x8*)&sBl[srw][sc0 + 8] = *(const u16x8*)(pbl + 8);
    }
    __syncthreads();
    bf16x8 ah[4], al[4], bh_[4], bl[4];
#pragma unroll
    for (int m = 0; m < 4; ++m) {
      const int r = wm + m * 16 + (lane & 15);
      const int c = (lane >> 4) * 8;
      ah[m] = *(const bf16x8*)&sAh[r][c];
      al[m] = *(const bf16x8*)&sAl[r][c];
    }
#pragma unroll
    for (int n = 0; n < 4; ++n) {
      const int r = wn + n * 16 + (lane & 15);
      const int c = (lane >> 4) * 8;
      bh_[n] = *(const bf16x8*)&sBh[r][c];
      bl[n]  = *(const bf16x8*)&sBl[r][c];
    }
#pragma unroll
    for (int m = 0; m < 4; ++m)
#pragma unroll
      for (int n = 0; n < 4; ++n) {
        f32x4 a = acc[m][n];
        a = __builtin_amdgcn_mfma_f32_16x16x32_bf16(ah[m], bh_[n], a, 0, 0, 0);
        a = __builtin_amdgcn_mfma_f32_16x16x32_bf16(ah[m], bl[n], a, 0, 0, 0);
        a = __builtin_amdgcn_mfma_f32_16x16x32_bf16(al[m], bh_[n], a, 0, 0, 0);
        acc[m][n] = a;
      }
    __syncthreads();
  }

#pragma unroll
  for (int m = 0; m < 4; ++m)
#pragma unroll
    for (int i = 0; i < 4; ++i) {
      int gr = m0 + wm + m * 16 + (lane >> 4) * 4 + i;
      float* crow = C + (size_t)gr * N + n0 + wn + (lane & 15);
#pragma unroll
      for (int n = 0; n < 4; ++n) crow[n * 16] = acc[m][n][i];
    }
}

// ---------------- RMSNorm + RoPE + V cast + gate ----------------
// Q is pre-scaled by 0.125*log2(e) so attention can use exp2 directly.
#define QSCALE 0.18033688011112042f
__global__ __launch_bounds__(256) void norm_rope_gate(const float* __restrict__ qkv, const float* __restrict__ x,
                                                      const float* __restrict__ qw, const float* __restrict__ kw,
                                                      const float* __restrict__ gw,
                                                      u16* __restrict__ Q, u16* __restrict__ Kd,
                                                      u16* __restrict__ V, float* __restrict__ gate) {
  const int t = blockIdx.x * 4 + (threadIdx.x >> 6);
  const int lane = threadIdx.x & 63;
  const int b = t >> 11, s = t & 2047;
  const float* base = qkv + (size_t)t * 1536;
  const int ri = lane >> 1;
  float sn, cs;
  sincosf((float)s * expf(-(float)ri * (9.21034037198f / 32.0f)), &sn, &cs);
  const float qwl = qw[lane], kwl = kw[lane];

  for (int hh = 0; hh < 16; ++hh) {
    float v = base[hh * 64 + lane];
    float ss = v * v;
#pragma unroll
    for (int off = 32; off >= 1; off >>= 1) ss += __shfl_xor(ss, off);
    float r = rsqrtf(ss * (1.0f / 64.0f) + 1.1920929e-7f);
    float xn = v * r * qwl;
    float p = __shfl_xor(xn, 1);
    float outv = ((lane & 1) == 0) ? (xn * cs - p * sn) : (xn * cs + p * sn);
    Q[((size_t)(b * 16 + hh) * 2048 + s) * 64 + lane] = f2bf(outv * QSCALE);
  }
  for (int hh = 0; hh < 4; ++hh) {
    float v = base[1024 + hh * 64 + lane];
    float ss = v * v;
#pragma unroll
    for (int off = 32; off >= 1; off >>= 1) ss += __shfl_xor(ss, off);
    float r = rsqrtf(ss * (1.0f / 64.0f) + 1.1920929e-7f);
    float xn = v * r * kwl;
    float p = __shfl_xor(xn, 1);
    float outv = ((lane & 1) == 0) ? (xn * cs - p * sn) : (xn * cs + p * sn);
    Kd[((size_t)(b * 4 + hh) * 2048 + s) * 64 + lane] = f2bf(outv);
    V[((size_t)(b * 4 + hh) * 2048 + s) * 64 + lane] = f2bf(base[1280 + hh * 64 + lane]);
  }
  if (lane < 16) {
    float g = 0.f;
#pragma unroll
    for (int j = 0; j < 12; ++j) g += x[(size_t)t * 1024 + j] * gw[lane * 12 + j];
    gate[(size_t)t * 16 + lane] = 1.0f / (1.0f + __expf(-g));
  }
}

// ---------------- V transpose: [bh][s][d] -> [bh][d][s] ----------------
__global__ __launch_bounds__(256) void transpose_v64(const u16* __restrict__ V, u16* __restrict__ Vt) {
  __shared__ __align__(16) u16 tile[64][72];
  const int st = blockIdx.x, bh = blockIdx.y;
  const u16* src = V + ((size_t)bh * 2048 + st * 64) * 64;
  u16* dst = Vt + (size_t)bh * 64 * 2048 + st * 64;
  const int t = threadIdx.x;
  const int r = t >> 2, c0 = (t & 3) * 16;
#pragma unroll
  for (int j = 0; j < 2; ++j)
    *(u16x8*)&tile[r][c0 + j * 8] = *(const u16x8*)&src[(size_t)r * 64 + c0 + j * 8];
  __syncthreads();
  u16 tmp[16];
#pragma unroll
  for (int j = 0; j < 16; ++j) tmp[j] = tile[c0 + j][r];
#pragma unroll
  for (int j = 0; j < 2; ++j)
    *(u16x8*)&dst[(size_t)r * 2048 + c0 + j * 8] = *(const u16x8*)&tmp[j * 8];
}

// ---------------- Flash attention, causal GQA — wave-independent, barrier-free ----------------
// grid (S/64, B*H); 4 waves; wave w owns q rows [q0+16w, q0+16w+16).
// K and V^T fragments are read directly from global (L2-resident); only P
// round-trips through a per-wave LDS region (no __syncthreads anywhere).
__global__ __launch_bounds__(256, 4) void attn_fwd(const u16* __restrict__ Q, const u16* __restrict__ Kg,
                                                   const u16* __restrict__ Vt, const float* __restrict__ gate,
                                                   u16* __restrict__ attnh, u16* __restrict__ attnl) {
  __shared__ __align__(16) u16 sP[4][16][72];

  const int tid = threadIdx.x;
  const int w = tid >> 6, lane = tid & 63;
  const int qi = blockIdx.x;
  const int q0 = qi * 64;
  const int bh = blockIdx.y;
  const int b = bh >> 4, h = bh & 15;
  const int kvh = h >> 2;

  const u16* Qp = Q + (size_t)(b * 16 + h) * 2048 * 64;
  // per-lane fragment bases
  const u16* Kp = Kg + (size_t)(b * 4 + kvh) * 2048 * 64 + (lane & 15) * 64 + (lane >> 4) * 8;
  const u16* Vp = Vt + (size_t)(b * 4 + kvh) * 64 * 2048 + (size_t)(lane & 15) * 2048 + (lane >> 4) * 8;

  bf16x8 qa0, qa1;
  {
    const u16* qrow = Qp + (size_t)(q0 + w * 16 + (lane & 15)) * 64 + (lane >> 4) * 8;
    qa0 = *(const bf16x8*)qrow;
    qa1 = *(const bf16x8*)(qrow + 32);
  }

  f32x4 acc[4] = {};
  float m_run[4], l_run[4];
#pragma unroll
  for (int i = 0; i < 4; ++i) { m_run[i] = -1e30f; l_run[i] = 0.f; }

  for (int t = 0; t <= qi; ++t) {
    const int kv0 = t * 64;

    // S' = (QK^T) pre-scaled (QSCALE folded into Q)
    f32x4 sc[4];
#pragma unroll
    for (int ct = 0; ct < 4; ++ct) {
      const u16* kp = Kp + (size_t)(kv0 + ct * 16) * 64;
      bf16x8 k0 = *(const bf16x8*)kp;
      bf16x8 k1 = *(const bf16x8*)(kp + 32);
      f32x4 s4 = {};
      s4 = __builtin_amdgcn_mfma_f32_16x16x32_bf16(qa0, k0, s4, 0, 0, 0);
      s4 = __builtin_amdgcn_mfma_f32_16x16x32_bf16(qa1, k1, s4, 0, 0, 0);
      sc[ct] = s4;
    }

    float pmax[4] = {-1e30f, -1e30f, -1e30f, -1e30f};
    if (t == qi) {
      // diagonal tile: causal mask
      const int colb = kv0 + (lane & 15);
      const int rowb = q0 + w * 16 + (lane >> 4) * 4;
#pragma unroll
      for (int ct = 0; ct < 4; ++ct)
#pragma unroll
        for (int i = 0; i < 4; ++i) {
          float v = (colb + ct * 16 <= rowb + i) ? sc[ct][i] : -1e30f;
          sc[ct][i] = v;
          pmax[i] = fmaxf(pmax[i], v);
        }
    } else {
#pragma unroll
      for (int ct = 0; ct < 4; ++ct)
#pragma unroll
        for (int i = 0; i < 4; ++i) pmax[i] = fmaxf(pmax[i], sc[ct][i]);
    }
#pragma unroll
    for (int off = 8; off >= 1; off >>= 1)
#pragma unroll
      for (int i = 0; i < 4; ++i) pmax[i] = fmaxf(pmax[i], __shfl_xor(pmax[i], off));

    float alpha[4];
#pragma unroll
    for (int i = 0; i < 4; ++i) {
      float mn = fmaxf(m_run[i], pmax[i]);
      alpha[i] = exp2f(m_run[i] - mn);
      m_run[i] = mn;
    }
    u16 pb[4][4];
    float rs[4] = {0.f, 0.f, 0.f, 0.f};
#pragma unroll
    for (int ct = 0; ct < 4; ++ct)
#pragma unroll
      for (int i = 0; i < 4; ++i) {
        float p = exp2f(sc[ct][i] - m_run[i]);
        u16 pbits = f2bf(p);
        pb[ct][i] = pbits;
        rs[i] += bf2f(pbits);
      }
#pragma unroll
    for (int i = 0; i < 4; ++i) l_run[i] = l_run[i] * alpha[i] + rs[i];
#pragma unroll
    for (int n = 0; n < 4; ++n)
#pragma unroll
      for (int i = 0; i < 4; ++i) acc[n][i] *= alpha[i];

    // P -> per-wave LDS (wave-internal exchange; no barrier needed)
#pragma unroll
    for (int ct = 0; ct < 4; ++ct)
#pragma unroll
      for (int i = 0; i < 4; ++i)
        sP[w][(lane >> 4) * 4 + i][ct * 16 + (lane & 15)] = pb[ct][i];

    bf16x8 pa0 = *(const bf16x8*)&sP[w][lane & 15][(lane >> 4) * 8];
    bf16x8 pa1 = *(const bf16x8*)&sP[w][lane & 15][32 + (lane >> 4) * 8];

#pragma unroll
    for (int n = 0; n < 4; ++n) {
      const u16* vp = Vp + n * 16 * 2048 + kv0;
      bf16x8 v0 = *(const bf16x8*)vp;
      bf16x8 v1 = *(const bf16x8*)(vp + 32);
      acc[n] = __builtin_amdgcn_mfma_f32_16x16x32_bf16(pa0, v0, acc[n], 0, 0, 0);
      acc[n] = __builtin_amdgcn_mfma_f32_16x16x32_bf16(pa1, v1, acc[n], 0, 0, 0);
    }
  }

  // final denominator reduce across the 16-lane column group
#pragma unroll
  for (int off = 8; off >= 1; off >>= 1)
#pragma unroll
    for (int i = 0; i < 4; ++i) l_run[i] += __shfl_xor(l_run[i], off);

  // epilogue: O = acc / l * gate, split-write hi/lo bf16 [token][h*64+d]
#pragma unroll
  for (int i = 0; i < 4; ++i) {
    int srowg = q0 + w * 16 + (lane >> 4) * 4 + i;
    float g = gate[((size_t)b * 2048 + srowg) * 16 + h];
    float inv = 1.0f / l_run[i];
    size_t rowoff = ((size_t)b * 2048 + srowg) * 1024 + h * 64 + (lane & 15);
    u16* oh = attnh + rowoff;
    u16* ol = attnl + rowoff;
#pragma unroll
    for (int n = 0; n < 4; ++n) {
      float o = acc[n][i] * inv * g;
      u16 hbits = f2bf(o);
      oh[n * 16] = hbits;
      ol[n * 16] = f2bf(o - bf2f(hbits));
    }
  }
}

// ---------------- launch ----------------
extern "C" void kernel_launch(void* const* d_in, const int* in_sizes, int n_in,
                              void* d_out, int out_size, void* d_ws, size_t ws_size,
                              hipStream_t stream) {
  const float* x  = (const float*)d_in[0];
  const float* Wf = (const float*)d_in[1];
  const float* qw = (const float*)d_in[2];
  const float* kw = (const float*)d_in[3];
  const float* gw = (const float*)d_in[4];
  float* out = (float*)d_out;

  char* ws = (char*)d_ws;
  size_t off = 0;
  auto alloc = [&](size_t bytes) { void* p = ws + off; off += (bytes + 255) & ~(size_t)255; return p; };

  u16*   xh   = (u16*)alloc((size_t)4096 * 1024 * 2);
  u16*   xl   = (u16*)alloc((size_t)4096 * 1024 * 2);
  u16*   wh   = (u16*)alloc((size_t)2560 * 1024 * 2);
  u16*   wl   = (u16*)alloc((size_t)2560 * 1024 * 2);
  float* qkv  = (float*)alloc((size_t)4096 * 1536 * 4);
  u16*   Qb   = (u16*)alloc((size_t)2 * 16 * 2048 * 64 * 2);
  u16*   Kb   = (u16*)alloc((size_t)2 * 4 * 2048 * 64 * 2);
  u16*   Vb   = (u16*)alloc((size_t)2 * 4 * 2048 * 64 * 2);
  u16*   Vtb  = (u16*)alloc((size_t)2 * 4 * 2048 * 64 * 2);
  float* gate = (float*)alloc((size_t)2 * 2048 * 16 * 4);
  // attn hi/lo alias x hi/lo (dead after the QKV GEMM)
  u16*   attnh = xh;
  u16*   attnl = xl;

  cvt_split<<<dim3(4096), dim3(256), 0, stream>>>(x, xh, xl, 4096 * 1024 / 4);
  cvt_split<<<dim3(2560), dim3(256), 0, stream>>>(Wf, wh, wl, 2560 * 1024 / 4);
  gemm_nt<<<dim3(32, 12), dim3(256), 0, stream>>>(xh, wh, qkv, 4096, 1536, 1024);
  norm_rope_gate<<<dim3(1024), dim3(256), 0, stream>>>(qkv, x, qw, kw, gw, Qb, Kb, Vb, gate);
  transpose_v64<<<dim3(32, 8), dim3(256), 0, stream>>>(Vb, Vtb);
  attn_fwd<<<dim3(32, 32), dim3(256), 0, stream>>>(Qb, Kb, Vtb, gate, attnh, attnl);
  gemm_split<<<dim3(32, 8), dim3(256), 0, stream>>>(attnh, attnl, wh + (size_t)1536 * 1024, wl + (size_t)1536 * 1024,
                                                    out, 4096, 1024, 1024);
}

// Round 5
// 204.051 us; speedup vs baseline: 1.6439x; 1.6439x over previous
//
#include <hip/hip_runtime.h>
#include <math.h>

typedef unsigned short u16;
typedef __bf16 bf16x8 __attribute__((ext_vector_type(8)));
typedef float f32x4 __attribute__((ext_vector_type(4)));
typedef unsigned short u16x8 __attribute__((ext_vector_type(8)));
typedef unsigned short u16x4 __attribute__((ext_vector_type(4)));

static __device__ __forceinline__ u16 f2bf(float f) {
  unsigned int u = __builtin_bit_cast(unsigned int, f);
  u = (u + 0x7FFFu + ((u >> 16) & 1u)) >> 16;
  return (u16)u;
}
static __device__ __forceinline__ float bf2f(u16 u) {
  unsigned int x = ((unsigned int)u) << 16;
  return __builtin_bit_cast(float, x);
}
static __device__ __forceinline__ u16 f2bfh(float f) {
  __bf16 b = (__bf16)f;
  return __builtin_bit_cast(u16, b);
}

// ---------------- f32 -> bf16 convert ----------------
__global__ __launch_bounds__(256) void cvt_bf16(const float* __restrict__ src, u16* __restrict__ dst, int n4) {
  int idx = blockIdx.x * 256 + threadIdx.x;
  if (idx < n4) {
    float4 v = ((const float4*)src)[idx];
    ushort4 r;
    r.x = f2bf(v.x); r.y = f2bf(v.y); r.z = f2bf(v.z); r.w = f2bf(v.w);
    ((ushort4*)dst)[idx] = r;
  }
}

// ---------------- plain bf16 NT GEMM: C = A * B^T, f32 out ----------------
// 128x128 tile, BK=32, 256 threads (4 waves, each 64x64).
__global__ __launch_bounds__(256) void gemm_nt(const u16* __restrict__ A, const u16* __restrict__ B,
                                               float* __restrict__ C, int M, int N, int K) {
  __shared__ __align__(16) u16 sA[128][40];
  __shared__ __align__(16) u16 sB[128][40];
  const int tid = threadIdx.x;
  const int w = tid >> 6, lane = tid & 63;
  const int m0 = blockIdx.x * 128, n0 = blockIdx.y * 128;
  const int wm = (w >> 1) * 64, wn = (w & 1) * 64;

  f32x4 acc[4][4] = {};
  const int srw = tid >> 1, sc0 = (tid & 1) * 16;

  for (int k0 = 0; k0 < K; k0 += 32) {
    {
      const u16* pa = A + (size_t)(m0 + srw) * K + k0 + sc0;
      const u16* pb = B + (size_t)(n0 + srw) * K + k0 + sc0;
      *(u16x8*)&sA[srw][sc0]     = *(const u16x8*)pa;
      *(u16x8*)&sA[srw][sc0 + 8] = *(const u16x8*)(pa + 8);
      *(u16x8*)&sB[srw][sc0]     = *(const u16x8*)pb;
      *(u16x8*)&sB[srw][sc0 + 8] = *(const u16x8*)(pb + 8);
    }
    __syncthreads();
    bf16x8 af[4], bfr[4];
#pragma unroll
    for (int m = 0; m < 4; ++m) af[m] = *(const bf16x8*)&sA[wm + m * 16 + (lane & 15)][(lane >> 4) * 8];
#pragma unroll
    for (int n = 0; n < 4; ++n) bfr[n] = *(const bf16x8*)&sB[wn + n * 16 + (lane & 15)][(lane >> 4) * 8];
#pragma unroll
    for (int m = 0; m < 4; ++m)
#pragma unroll
      for (int n = 0; n < 4; ++n)
        acc[m][n] = __builtin_amdgcn_mfma_f32_16x16x32_bf16(af[m], bfr[n], acc[m][n], 0, 0, 0);
    __syncthreads();
  }

#pragma unroll
  for (int m = 0; m < 4; ++m)
#pragma unroll
    for (int i = 0; i < 4; ++i) {
      int gr = m0 + wm + m * 16 + (lane >> 4) * 4 + i;
      float* crow = C + (size_t)gr * N + n0 + wn + (lane & 15);
#pragma unroll
      for (int n = 0; n < 4; ++n) crow[n * 16] = acc[m][n][i];
    }
}

// ---------------- RMSNorm + RoPE + V cast + gate ----------------
// Q is pre-scaled by 0.125*log2(e) so attention can use exp2 directly.
#define QSCALE 0.18033688011112042f
__global__ __launch_bounds__(256) void norm_rope_gate(const float* __restrict__ qkv, const float* __restrict__ x,
                                                      const float* __restrict__ qw, const float* __restrict__ kw,
                                                      const float* __restrict__ gw,
                                                      u16* __restrict__ Q, u16* __restrict__ Kd,
                                                      u16* __restrict__ V, float* __restrict__ gate) {
  const int t = blockIdx.x * 4 + (threadIdx.x >> 6);
  const int lane = threadIdx.x & 63;
  const int b = t >> 11, s = t & 2047;
  const float* base = qkv + (size_t)t * 1536;
  const int ri = lane >> 1;
  float sn, cs;
  sincosf((float)s * expf(-(float)ri * (9.21034037198f / 32.0f)), &sn, &cs);
  const float qwl = qw[lane], kwl = kw[lane];

  for (int hh = 0; hh < 16; ++hh) {
    float v = base[hh * 64 + lane];
    float ss = v * v;
#pragma unroll
    for (int off = 32; off >= 1; off >>= 1) ss += __shfl_xor(ss, off);
    float r = rsqrtf(ss * (1.0f / 64.0f) + 1.1920929e-7f);
    float xn = v * r * qwl;
    float p = __shfl_xor(xn, 1);
    float outv = ((lane & 1) == 0) ? (xn * cs - p * sn) : (xn * cs + p * sn);
    Q[((size_t)(b * 16 + hh) * 2048 + s) * 64 + lane] = f2bf(outv * QSCALE);
  }
  for (int hh = 0; hh < 4; ++hh) {
    float v = base[1024 + hh * 64 + lane];
    float ss = v * v;
#pragma unroll
    for (int off = 32; off >= 1; off >>= 1) ss += __shfl_xor(ss, off);
    float r = rsqrtf(ss * (1.0f / 64.0f) + 1.1920929e-7f);
    float xn = v * r * kwl;
    float p = __shfl_xor(xn, 1);
    float outv = ((lane & 1) == 0) ? (xn * cs - p * sn) : (xn * cs + p * sn);
    Kd[((size_t)(b * 4 + hh) * 2048 + s) * 64 + lane] = f2bf(outv);
    V[((size_t)(b * 4 + hh) * 2048 + s) * 64 + lane] = f2bf(base[1280 + hh * 64 + lane]);
  }
  if (lane < 16) {
    float g = 0.f;
#pragma unroll
    for (int j = 0; j < 12; ++j) g += x[(size_t)t * 1024 + j] * gw[lane * 12 + j];
    gate[(size_t)t * 16 + lane] = 1.0f / (1.0f + __expf(-g));
  }
}

// ---------------- V transpose: [bh][s][d] -> [bh][d][s] ----------------
__global__ __launch_bounds__(256) void transpose_v64(const u16* __restrict__ V, u16* __restrict__ Vt) {
  __shared__ __align__(16) u16 tile[64][72];
  const int st = blockIdx.x, bh = blockIdx.y;
  const u16* src = V + ((size_t)bh * 2048 + st * 64) * 64;
  u16* dst = Vt + (size_t)bh * 64 * 2048 + st * 64;
  const int t = threadIdx.x;
  const int r = t >> 2, c0 = (t & 3) * 16;
#pragma unroll
  for (int j = 0; j < 2; ++j)
    *(u16x8*)&tile[r][c0 + j * 8] = *(const u16x8*)&src[(size_t)r * 64 + c0 + j * 8];
  __syncthreads();
  u16 tmp[16];
#pragma unroll
  for (int j = 0; j < 16; ++j) tmp[j] = tile[c0 + j][r];
#pragma unroll
  for (int j = 0; j < 2; ++j)
    *(u16x8*)&dst[(size_t)r * 2048 + c0 + j * 8] = *(const u16x8*)&tmp[j * 8];
}

// ---------------- Flash attention, causal GQA — staged, double-buffered, 1 barrier/tile ----
// grid (S/64, B*H); 4 waves; wave w owns q rows [q0+16w, q0+16w+16).
__global__ __launch_bounds__(256) void attn_fwd(const u16* __restrict__ Q, const u16* __restrict__ Kg,
                                                const u16* __restrict__ Vt, const float* __restrict__ gate,
                                                u16* __restrict__ attnh) {
  __shared__ __align__(16) u16 sK[2][64][72];   // K[kv][d]
  __shared__ __align__(16) u16 sV[2][64][72];   // Vt[d][kv]
  __shared__ __align__(16) u16 sP[4][16][68];   // stride 68: 4 lane-groups hit disjoint banks

  const int tid = threadIdx.x;
  const int w = tid >> 6, lane = tid & 63;
  const int l15 = lane & 15, lg = lane >> 4;
  const int qi = blockIdx.x, q0 = qi * 64;
  const int bh = blockIdx.y, b = bh >> 4, h = bh & 15, kvh = h >> 2;

  const u16* Qp = Q + (size_t)(b * 16 + h) * 2048 * 64;
  const u16* Kp = Kg + (size_t)(b * 4 + kvh) * 2048 * 64;
  const u16* Vp = Vt + (size_t)(b * 4 + kvh) * 64 * 2048;

  bf16x8 qa0, qa1;
  {
    const u16* qrow = Qp + (size_t)(q0 + w * 16 + l15) * 64 + lg * 8;
    qa0 = *(const bf16x8*)qrow;
    qa1 = *(const bf16x8*)(qrow + 32);
  }

  f32x4 acc[4] = {};
  float m_run[4], l_run[4];
#pragma unroll
  for (int i = 0; i < 4; ++i) { m_run[i] = -1e30f; l_run[i] = 0.f; }

  const int srw = tid >> 2, sc0 = (tid & 3) * 16;
  const u16* kgp = Kp + (size_t)srw * 64 + sc0;
  const u16* vgp = Vp + (size_t)srw * 2048 + sc0;

  // prologue: stage tile 0 into buffer 0
  u16x8 kr0 = *(const u16x8*)kgp, kr1 = *(const u16x8*)(kgp + 8);
  u16x8 vr0 = *(const u16x8*)vgp, vr1 = *(const u16x8*)(vgp + 8);
  *(u16x8*)&sK[0][srw][sc0] = kr0; *(u16x8*)&sK[0][srw][sc0 + 8] = kr1;
  *(u16x8*)&sV[0][srw][sc0] = vr0; *(u16x8*)&sV[0][srw][sc0 + 8] = vr1;
  __syncthreads();

  for (int t = 0; t <= qi; ++t) {
    const int buf = t & 1;

    // T14: issue next tile's global loads now; consume after compute.
    if (t < qi) {
      const u16* kg = kgp + (size_t)(t + 1) * 64 * 64;
      const u16* vg = vgp + (t + 1) * 64;
      kr0 = *(const u16x8*)kg; kr1 = *(const u16x8*)(kg + 8);
      vr0 = *(const u16x8*)vg; vr1 = *(const u16x8*)(vg + 8);
    }

    // S' = Q K^T (pre-scaled; QSCALE folded into Q)
    f32x4 sc[4];
#pragma unroll
    for (int ct = 0; ct < 4; ++ct) {
      const int r = ct * 16 + l15;
      bf16x8 k0 = *(const bf16x8*)&sK[buf][r][lg * 8];
      bf16x8 k1 = *(const bf16x8*)&sK[buf][r][32 + lg * 8];
      f32x4 s4 = {};
      s4 = __builtin_amdgcn_mfma_f32_16x16x32_bf16(qa0, k0, s4, 0, 0, 0);
      s4 = __builtin_amdgcn_mfma_f32_16x16x32_bf16(qa1, k1, s4, 0, 0, 0);
      sc[ct] = s4;
    }

    float pmax[4] = {-1e30f, -1e30f, -1e30f, -1e30f};
    if (t == qi) {
      const int colb = t * 64 + l15;
      const int rowb = q0 + w * 16 + lg * 4;
#pragma unroll
      for (int ct = 0; ct < 4; ++ct)
#pragma unroll
        for (int i = 0; i < 4; ++i) {
          float v = (colb + ct * 16 <= rowb + i) ? sc[ct][i] : -1e30f;
          sc[ct][i] = v;
          pmax[i] = fmaxf(pmax[i], v);
        }
    } else {
#pragma unroll
      for (int ct = 0; ct < 4; ++ct)
#pragma unroll
        for (int i = 0; i < 4; ++i) pmax[i] = fmaxf(pmax[i], sc[ct][i]);
    }
#pragma unroll
    for (int off = 8; off >= 1; off >>= 1)
#pragma unroll
      for (int i = 0; i < 4; ++i) pmax[i] = fmaxf(pmax[i], __shfl_xor(pmax[i], off));

    float alpha[4];
#pragma unroll
    for (int i = 0; i < 4; ++i) {
      float mn = fmaxf(m_run[i], pmax[i]);
      alpha[i] = exp2f(m_run[i] - mn);
      m_run[i] = mn;
    }
    u16 pb[4][4];
    float rs[4] = {0.f, 0.f, 0.f, 0.f};
#pragma unroll
    for (int ct = 0; ct < 4; ++ct)
#pragma unroll
      for (int i = 0; i < 4; ++i) {
        float p = exp2f(sc[ct][i] - m_run[i]);
        u16 pbits = f2bfh(p);
        pb[ct][i] = pbits;
        rs[i] += bf2f(pbits);
      }
#pragma unroll
    for (int i = 0; i < 4; ++i) l_run[i] = l_run[i] * alpha[i] + rs[i];
#pragma unroll
    for (int n = 0; n < 4; ++n)
#pragma unroll
      for (int i = 0; i < 4; ++i) acc[n][i] *= alpha[i];

    // P -> per-wave LDS (wave-internal; compiler-ordered lgkmcnt, no barrier)
#pragma unroll
    for (int ct = 0; ct < 4; ++ct)
#pragma unroll
      for (int i = 0; i < 4; ++i)
        sP[w][lg * 4 + i][ct * 16 + l15] = pb[ct][i];

    u16x4 p00 = *(const u16x4*)&sP[w][l15][lg * 8];
    u16x4 p01 = *(const u16x4*)&sP[w][l15][lg * 8 + 4];
    u16x4 p10 = *(const u16x4*)&sP[w][l15][32 + lg * 8];
    u16x4 p11 = *(const u16x4*)&sP[w][l15][32 + lg * 8 + 4];
    bf16x8 pa0 = __builtin_bit_cast(bf16x8, __builtin_shufflevector(p00, p01, 0, 1, 2, 3, 4, 5, 6, 7));
    bf16x8 pa1 = __builtin_bit_cast(bf16x8, __builtin_shufflevector(p10, p11, 0, 1, 2, 3, 4, 5, 6, 7));

#pragma unroll
    for (int n = 0; n < 4; ++n) {
      const int r = n * 16 + l15;
      bf16x8 v0 = *(const bf16x8*)&sV[buf][r][lg * 8];
      bf16x8 v1 = *(const bf16x8*)&sV[buf][r][32 + lg * 8];
      acc[n] = __builtin_amdgcn_mfma_f32_16x16x32_bf16(pa0, v0, acc[n], 0, 0, 0);
      acc[n] = __builtin_amdgcn_mfma_f32_16x16x32_bf16(pa1, v1, acc[n], 0, 0, 0);
    }

    // write prefetched tile into the other buffer, single barrier per tile
    if (t < qi) {
      *(u16x8*)&sK[buf ^ 1][srw][sc0] = kr0; *(u16x8*)&sK[buf ^ 1][srw][sc0 + 8] = kr1;
      *(u16x8*)&sV[buf ^ 1][srw][sc0] = vr0; *(u16x8*)&sV[buf ^ 1][srw][sc0 + 8] = vr1;
    }
    __syncthreads();
  }

  // deferred denominator reduce across the 16-lane column group
#pragma unroll
  for (int off = 8; off >= 1; off >>= 1)
#pragma unroll
    for (int i = 0; i < 4; ++i) l_run[i] += __shfl_xor(l_run[i], off);

  // epilogue: O = acc / l * gate, bf16 [token][h*64+d]
#pragma unroll
  for (int i = 0; i < 4; ++i) {
    int srowg = q0 + w * 16 + lg * 4 + i;
    float g = gate[((size_t)b * 2048 + srowg) * 16 + h];
    float inv = 1.0f / l_run[i];
    u16* orow = attnh + ((size_t)b * 2048 + srowg) * 1024 + h * 64 + l15;
#pragma unroll
    for (int n = 0; n < 4; ++n) orow[n * 16] = f2bfh(acc[n][i] * inv * g);
  }
}

// ---------------- launch ----------------
extern "C" void kernel_launch(void* const* d_in, const int* in_sizes, int n_in,
                              void* d_out, int out_size, void* d_ws, size_t ws_size,
                              hipStream_t stream) {
  const float* x  = (const float*)d_in[0];
  const float* Wf = (const float*)d_in[1];
  const float* qw = (const float*)d_in[2];
  const float* kw = (const float*)d_in[3];
  const float* gw = (const float*)d_in[4];
  float* out = (float*)d_out;

  char* ws = (char*)d_ws;
  size_t off = 0;
  auto alloc = [&](size_t bytes) { void* p = ws + off; off += (bytes + 255) & ~(size_t)255; return p; };

  u16*   xb   = (u16*)alloc((size_t)4096 * 1024 * 2);
  u16*   wb   = (u16*)alloc((size_t)2560 * 1024 * 2);
  float* qkv  = (float*)alloc((size_t)4096 * 1536 * 4);
  u16*   Qb   = (u16*)alloc((size_t)2 * 16 * 2048 * 64 * 2);
  u16*   Kb   = (u16*)alloc((size_t)2 * 4 * 2048 * 64 * 2);
  u16*   Vb   = (u16*)alloc((size_t)2 * 4 * 2048 * 64 * 2);
  u16*   Vtb  = (u16*)alloc((size_t)2 * 4 * 2048 * 64 * 2);
  float* gate = (float*)alloc((size_t)2 * 2048 * 16 * 4);
  // attn output aliases xb (x's bf16 copy is dead after the QKV GEMM)
  u16*   attnh = xb;

  cvt_bf16<<<dim3(4096), dim3(256), 0, stream>>>(x, xb, 4096 * 1024 / 4);
  cvt_bf16<<<dim3(2560), dim3(256), 0, stream>>>(Wf, wb, 2560 * 1024 / 4);
  gemm_nt<<<dim3(32, 12), dim3(256), 0, stream>>>(xb, wb, qkv, 4096, 1536, 1024);
  norm_rope_gate<<<dim3(1024), dim3(256), 0, stream>>>(qkv, x, qw, kw, gw, Qb, Kb, Vb, gate);
  transpose_v64<<<dim3(32, 8), dim3(256), 0, stream>>>(Vb, Vtb);
  attn_fwd<<<dim3(32, 32), dim3(256), 0, stream>>>(Qb, Kb, Vtb, gate, attnh);
  gemm_nt<<<dim3(32, 8), dim3(256), 0, stream>>>(attnh, wb + (size_t)1536 * 1024, out, 4096, 1024, 1024);
}

// Round 6
// 164.610 us; speedup vs baseline: 2.0377x; 1.2396x over previous
//
#include <hip/hip_runtime.h>
#include <math.h>

typedef unsigned short u16;
typedef __bf16 bf16x8 __attribute__((ext_vector_type(8)));
typedef float f32x4 __attribute__((ext_vector_type(4)));
typedef unsigned short u16x8 __attribute__((ext_vector_type(8)));
typedef unsigned short u16x4 __attribute__((ext_vector_type(4)));

static __device__ __forceinline__ u16 f2bf(float f) {
  unsigned int u = __builtin_bit_cast(unsigned int, f);
  u = (u + 0x7FFFu + ((u >> 16) & 1u)) >> 16;
  return (u16)u;
}
static __device__ __forceinline__ float bf2f(u16 u) {
  unsigned int x = ((unsigned int)u) << 16;
  return __builtin_bit_cast(float, x);
}
static __device__ __forceinline__ u16 f2bfh(float f) {
  __bf16 b = (__bf16)f;
  return __builtin_bit_cast(u16, b);
}

// ---------------- f32 -> bf16 convert ----------------
__global__ __launch_bounds__(256) void cvt_bf16(const float* __restrict__ src, u16* __restrict__ dst, int n4) {
  int idx = blockIdx.x * 256 + threadIdx.x;
  if (idx < n4) {
    float4 v = ((const float4*)src)[idx];
    ushort4 r;
    r.x = f2bf(v.x); r.y = f2bf(v.y); r.z = f2bf(v.z); r.w = f2bf(v.w);
    ((ushort4*)dst)[idx] = r;
  }
}

// ---------------- plain bf16 NT GEMM: C = A * B^T, f32 out ----------------
__global__ __launch_bounds__(256) void gemm_nt(const u16* __restrict__ A, const u16* __restrict__ B,
                                               float* __restrict__ C, int M, int N, int K) {
  __shared__ __align__(16) u16 sA[128][40];
  __shared__ __align__(16) u16 sB[128][40];
  const int tid = threadIdx.x;
  const int w = tid >> 6, lane = tid & 63;
  const int m0 = blockIdx.x * 128, n0 = blockIdx.y * 128;
  const int wm = (w >> 1) * 64, wn = (w & 1) * 64;

  f32x4 acc[4][4] = {};
  const int srw = tid >> 1, sc0 = (tid & 1) * 16;

  for (int k0 = 0; k0 < K; k0 += 32) {
    {
      const u16* pa = A + (size_t)(m0 + srw) * K + k0 + sc0;
      const u16* pb = B + (size_t)(n0 + srw) * K + k0 + sc0;
      *(u16x8*)&sA[srw][sc0]     = *(const u16x8*)pa;
      *(u16x8*)&sA[srw][sc0 + 8] = *(const u16x8*)(pa + 8);
      *(u16x8*)&sB[srw][sc0]     = *(const u16x8*)pb;
      *(u16x8*)&sB[srw][sc0 + 8] = *(const u16x8*)(pb + 8);
    }
    __syncthreads();
    bf16x8 af[4], bfr[4];
#pragma unroll
    for (int m = 0; m < 4; ++m) af[m] = *(const bf16x8*)&sA[wm + m * 16 + (lane & 15)][(lane >> 4) * 8];
#pragma unroll
    for (int n = 0; n < 4; ++n) bfr[n] = *(const bf16x8*)&sB[wn + n * 16 + (lane & 15)][(lane >> 4) * 8];
#pragma unroll
    for (int m = 0; m < 4; ++m)
#pragma unroll
      for (int n = 0; n < 4; ++n)
        acc[m][n] = __builtin_amdgcn_mfma_f32_16x16x32_bf16(af[m], bfr[n], acc[m][n], 0, 0, 0);
    __syncthreads();
  }

#pragma unroll
  for (int m = 0; m < 4; ++m)
#pragma unroll
    for (int i = 0; i < 4; ++i) {
      int gr = m0 + wm + m * 16 + (lane >> 4) * 4 + i;
      float* crow = C + (size_t)gr * N + n0 + wn + (lane & 15);
#pragma unroll
      for (int n = 0; n < 4; ++n) crow[n * 16] = acc[m][n][i];
    }
}

// ---------------- RMSNorm + RoPE + V cast + gate ----------------
#define QSCALE 0.18033688011112042f
__global__ __launch_bounds__(256) void norm_rope_gate(const float* __restrict__ qkv, const float* __restrict__ x,
                                                      const float* __restrict__ qw, const float* __restrict__ kw,
                                                      const float* __restrict__ gw,
                                                      u16* __restrict__ Q, u16* __restrict__ Kd,
                                                      u16* __restrict__ V, float* __restrict__ gate) {
  const int t = blockIdx.x * 4 + (threadIdx.x >> 6);
  const int lane = threadIdx.x & 63;
  const int b = t >> 11, s = t & 2047;
  const float* base = qkv + (size_t)t * 1536;
  const int ri = lane >> 1;
  float sn, cs;
  sincosf((float)s * expf(-(float)ri * (9.21034037198f / 32.0f)), &sn, &cs);
  const float qwl = qw[lane], kwl = kw[lane];

  for (int hh = 0; hh < 16; ++hh) {
    float v = base[hh * 64 + lane];
    float ss = v * v;
#pragma unroll
    for (int off = 32; off >= 1; off >>= 1) ss += __shfl_xor(ss, off);
    float r = rsqrtf(ss * (1.0f / 64.0f) + 1.1920929e-7f);
    float xn = v * r * qwl;
    float p = __shfl_xor(xn, 1);
    float outv = ((lane & 1) == 0) ? (xn * cs - p * sn) : (xn * cs + p * sn);
    Q[((size_t)(b * 16 + hh) * 2048 + s) * 64 + lane] = f2bf(outv * QSCALE);
  }
  for (int hh = 0; hh < 4; ++hh) {
    float v = base[1024 + hh * 64 + lane];
    float ss = v * v;
#pragma unroll
    for (int off = 32; off >= 1; off >>= 1) ss += __shfl_xor(ss, off);
    float r = rsqrtf(ss * (1.0f / 64.0f) + 1.1920929e-7f);
    float xn = v * r * kwl;
    float p = __shfl_xor(xn, 1);
    float outv = ((lane & 1) == 0) ? (xn * cs - p * sn) : (xn * cs + p * sn);
    Kd[((size_t)(b * 4 + hh) * 2048 + s) * 64 + lane] = f2bf(outv);
    V[((size_t)(b * 4 + hh) * 2048 + s) * 64 + lane] = f2bf(base[1280 + hh * 64 + lane]);
  }
  if (lane < 16) {
    float g = 0.f;
#pragma unroll
    for (int j = 0; j < 12; ++j) g += x[(size_t)t * 1024 + j] * gw[lane * 12 + j];
    gate[(size_t)t * 16 + lane] = 1.0f / (1.0f + __expf(-g));
  }
}

// ---------------- V transpose: [bh][s][d] -> [bh][d][s] ----------------
__global__ __launch_bounds__(256) void transpose_v64(const u16* __restrict__ V, u16* __restrict__ Vt) {
  __shared__ __align__(16) u16 tile[64][72];
  const int st = blockIdx.x, bh = blockIdx.y;
  const u16* src = V + ((size_t)bh * 2048 + st * 64) * 64;
  u16* dst = Vt + (size_t)bh * 64 * 2048 + st * 64;
  const int t = threadIdx.x;
  const int r = t >> 2, c0 = (t & 3) * 16;
#pragma unroll
  for (int j = 0; j < 2; ++j)
    *(u16x8*)&tile[r][c0 + j * 8] = *(const u16x8*)&src[(size_t)r * 64 + c0 + j * 8];
  __syncthreads();
  u16 tmp[16];
#pragma unroll
  for (int j = 0; j < 16; ++j) tmp[j] = tile[c0 + j][r];
#pragma unroll
  for (int j = 0; j < 2; ++j)
    *(u16x8*)&dst[(size_t)r * 2048 + c0 + j * 8] = *(const u16x8*)&tmp[j * 8];
}

// ---------------- Flash attention, causal GQA — paired q-tiles for load balance ----------
// grid (16, B*H). Block x owns q-tiles qiA=x and qiB=31-x (33 tile-units each, uniform).
// Single KV sweep t=0..qiB; K/V staged once, LDS fragments read once, feed both streams.
__global__ __launch_bounds__(256) void attn_fwd_pair(const u16* __restrict__ Q, const u16* __restrict__ Kg,
                                                     const u16* __restrict__ Vt, const float* __restrict__ gate,
                                                     u16* __restrict__ attnh) {
  __shared__ __align__(16) u16 sK[2][64][72];      // K[kv][d], double-buffered
  __shared__ __align__(16) u16 sV[2][64][72];      // Vt[d][kv]
  __shared__ __align__(16) u16 sP[2][4][16][68];   // per-stream, per-wave P buffer

  const int tid = threadIdx.x;
  const int w = tid >> 6, lane = tid & 63;
  const int l15 = lane & 15, lg = lane >> 4;
  const int qiA = blockIdx.x;          // 0..15
  const int qiB = 31 - qiA;            // 31..16
  const int bh = blockIdx.y, b = bh >> 4, h = bh & 15, kvh = h >> 2;

  const u16* Qp = Q + (size_t)(b * 16 + h) * 2048 * 64;
  const u16* Kp = Kg + (size_t)(b * 4 + kvh) * 2048 * 64;
  const u16* Vp = Vt + (size_t)(b * 4 + kvh) * 64 * 2048;

  const int q0s[2] = {qiA * 64, qiB * 64};
  bf16x8 qa[2][2];
#pragma unroll
  for (int s = 0; s < 2; ++s) {
    const u16* qrow = Qp + (size_t)(q0s[s] + w * 16 + l15) * 64 + lg * 8;
    qa[s][0] = *(const bf16x8*)qrow;
    qa[s][1] = *(const bf16x8*)(qrow + 32);
  }

  f32x4 acc[2][4] = {};
  float m_run[2][4], l_run[2][4];
#pragma unroll
  for (int s = 0; s < 2; ++s)
#pragma unroll
    for (int i = 0; i < 4; ++i) { m_run[s][i] = -1e30f; l_run[s][i] = 0.f; }

  const int srw = tid >> 2, sc0 = (tid & 3) * 16;
  const u16* kgp = Kp + (size_t)srw * 64 + sc0;
  const u16* vgp = Vp + (size_t)srw * 2048 + sc0;

  // prologue: stage tile 0 into buffer 0
  u16x8 kr0 = *(const u16x8*)kgp, kr1 = *(const u16x8*)(kgp + 8);
  u16x8 vr0 = *(const u16x8*)vgp, vr1 = *(const u16x8*)(vgp + 8);
  *(u16x8*)&sK[0][srw][sc0] = kr0; *(u16x8*)&sK[0][srw][sc0 + 8] = kr1;
  *(u16x8*)&sV[0][srw][sc0] = vr0; *(u16x8*)&sV[0][srw][sc0 + 8] = vr1;
  __syncthreads();

  for (int t = 0; t <= qiB; ++t) {
    const int buf = t & 1;

    // T14: issue next tile's global loads now; consume after compute.
    if (t < qiB) {
      const u16* kg = kgp + (size_t)(t + 1) * 64 * 64;
      const u16* vg = vgp + (t + 1) * 64;
      kr0 = *(const u16x8*)kg; kr1 = *(const u16x8*)(kg + 8);
      vr0 = *(const u16x8*)vg; vr1 = *(const u16x8*)(vg + 8);
    }

    // shared K / V fragments (read once, used by both streams)
    bf16x8 kf[4][2], vf[4][2];
#pragma unroll
    for (int ct = 0; ct < 4; ++ct) {
      const int r = ct * 16 + l15;
      kf[ct][0] = *(const bf16x8*)&sK[buf][r][lg * 8];
      kf[ct][1] = *(const bf16x8*)&sK[buf][r][32 + lg * 8];
      vf[ct][0] = *(const bf16x8*)&sV[buf][r][lg * 8];
      vf[ct][1] = *(const bf16x8*)&sV[buf][r][32 + lg * 8];
    }

#pragma unroll
    for (int s = 0; s < 2; ++s) {
      if (s == 0 && t > qiA) continue;     // stream A done (uniform branch)
      const int diag = s ? qiB : qiA;

      f32x4 sc[4];
#pragma unroll
      for (int ct = 0; ct < 4; ++ct) {
        f32x4 s4 = {};
        s4 = __builtin_amdgcn_mfma_f32_16x16x32_bf16(qa[s][0], kf[ct][0], s4, 0, 0, 0);
        s4 = __builtin_amdgcn_mfma_f32_16x16x32_bf16(qa[s][1], kf[ct][1], s4, 0, 0, 0);
        sc[ct] = s4;
      }

      float pmax[4] = {-1e30f, -1e30f, -1e30f, -1e30f};
      if (t == diag) {
        const int colb = t * 64 + l15;
        const int rowb = q0s[s] + w * 16 + lg * 4;
#pragma unroll
        for (int ct = 0; ct < 4; ++ct)
#pragma unroll
          for (int i = 0; i < 4; ++i) {
            float v = (colb + ct * 16 <= rowb + i) ? sc[ct][i] : -1e30f;
            sc[ct][i] = v;
            pmax[i] = fmaxf(pmax[i], v);
          }
      } else {
#pragma unroll
        for (int ct = 0; ct < 4; ++ct)
#pragma unroll
          for (int i = 0; i < 4; ++i) pmax[i] = fmaxf(pmax[i], sc[ct][i]);
      }
#pragma unroll
      for (int off = 8; off >= 1; off >>= 1)
#pragma unroll
        for (int i = 0; i < 4; ++i) pmax[i] = fmaxf(pmax[i], __shfl_xor(pmax[i], off));

      float alpha[4];
#pragma unroll
      for (int i = 0; i < 4; ++i) {
        float mn = fmaxf(m_run[s][i], pmax[i]);
        alpha[i] = exp2f(m_run[s][i] - mn);
        m_run[s][i] = mn;
      }
      u16 pb[4][4];
      float rs[4] = {0.f, 0.f, 0.f, 0.f};
#pragma unroll
      for (int ct = 0; ct < 4; ++ct)
#pragma unroll
        for (int i = 0; i < 4; ++i) {
          float p = exp2f(sc[ct][i] - m_run[s][i]);
          u16 pbits = f2bfh(p);
          pb[ct][i] = pbits;
          rs[i] += bf2f(pbits);
        }
#pragma unroll
      for (int i = 0; i < 4; ++i) l_run[s][i] = l_run[s][i] * alpha[i] + rs[i];
#pragma unroll
      for (int n = 0; n < 4; ++n)
#pragma unroll
        for (int i = 0; i < 4; ++i) acc[s][n][i] *= alpha[i];

      // P -> per-wave per-stream LDS (wave-internal; no barrier)
#pragma unroll
      for (int ct = 0; ct < 4; ++ct)
#pragma unroll
        for (int i = 0; i < 4; ++i)
          sP[s][w][lg * 4 + i][ct * 16 + l15] = pb[ct][i];

      u16x4 p00 = *(const u16x4*)&sP[s][w][l15][lg * 8];
      u16x4 p01 = *(const u16x4*)&sP[s][w][l15][lg * 8 + 4];
      u16x4 p10 = *(const u16x4*)&sP[s][w][l15][32 + lg * 8];
      u16x4 p11 = *(const u16x4*)&sP[s][w][l15][32 + lg * 8 + 4];
      bf16x8 pa0 = __builtin_bit_cast(bf16x8, __builtin_shufflevector(p00, p01, 0, 1, 2, 3, 4, 5, 6, 7));
      bf16x8 pa1 = __builtin_bit_cast(bf16x8, __builtin_shufflevector(p10, p11, 0, 1, 2, 3, 4, 5, 6, 7));

#pragma unroll
      for (int n = 0; n < 4; ++n) {
        acc[s][n] = __builtin_amdgcn_mfma_f32_16x16x32_bf16(pa0, vf[n][0], acc[s][n], 0, 0, 0);
        acc[s][n] = __builtin_amdgcn_mfma_f32_16x16x32_bf16(pa1, vf[n][1], acc[s][n], 0, 0, 0);
      }
    }

    // write prefetched tile into the other buffer, single barrier per tile
    if (t < qiB) {
      *(u16x8*)&sK[buf ^ 1][srw][sc0] = kr0; *(u16x8*)&sK[buf ^ 1][srw][sc0 + 8] = kr1;
      *(u16x8*)&sV[buf ^ 1][srw][sc0] = vr0; *(u16x8*)&sV[buf ^ 1][srw][sc0 + 8] = vr1;
    }
    __syncthreads();
  }

  // epilogue: deferred denominator reduce + gated write, both streams
#pragma unroll
  for (int s = 0; s < 2; ++s) {
#pragma unroll
    for (int off = 8; off >= 1; off >>= 1)
#pragma unroll
      for (int i = 0; i < 4; ++i) l_run[s][i] += __shfl_xor(l_run[s][i], off);
#pragma unroll
    for (int i = 0; i < 4; ++i) {
      int srowg = q0s[s] + w * 16 + lg * 4 + i;
      float g = gate[((size_t)b * 2048 + srowg) * 16 + h];
      float inv = 1.0f / l_run[s][i];
      u16* orow = attnh + ((size_t)b * 2048 + srowg) * 1024 + h * 64 + l15;
#pragma unroll
      for (int n = 0; n < 4; ++n) orow[n * 16] = f2bfh(acc[s][n][i] * inv * g);
    }
  }
}

// ---------------- launch ----------------
extern "C" void kernel_launch(void* const* d_in, const int* in_sizes, int n_in,
                              void* d_out, int out_size, void* d_ws, size_t ws_size,
                              hipStream_t stream) {
  const float* x  = (const float*)d_in[0];
  const float* Wf = (const float*)d_in[1];
  const float* qw = (const float*)d_in[2];
  const float* kw = (const float*)d_in[3];
  const float* gw = (const float*)d_in[4];
  float* out = (float*)d_out;

  char* ws = (char*)d_ws;
  size_t off = 0;
  auto alloc = [&](size_t bytes) { void* p = ws + off; off += (bytes + 255) & ~(size_t)255; return p; };

  u16*   xb   = (u16*)alloc((size_t)4096 * 1024 * 2);
  u16*   wb   = (u16*)alloc((size_t)2560 * 1024 * 2);
  float* qkv  = (float*)alloc((size_t)4096 * 1536 * 4);
  u16*   Qb   = (u16*)alloc((size_t)2 * 16 * 2048 * 64 * 2);
  u16*   Kb   = (u16*)alloc((size_t)2 * 4 * 2048 * 64 * 2);
  u16*   Vb   = (u16*)alloc((size_t)2 * 4 * 2048 * 64 * 2);
  u16*   Vtb  = (u16*)alloc((size_t)2 * 4 * 2048 * 64 * 2);
  float* gate = (float*)alloc((size_t)2 * 2048 * 16 * 4);
  // attn output aliases xb (x's bf16 copy is dead after the QKV GEMM)
  u16*   attnh = xb;

  cvt_bf16<<<dim3(4096), dim3(256), 0, stream>>>(x, xb, 4096 * 1024 / 4);
  cvt_bf16<<<dim3(2560), dim3(256), 0, stream>>>(Wf, wb, 2560 * 1024 / 4);
  gemm_nt<<<dim3(32, 12), dim3(256), 0, stream>>>(xb, wb, qkv, 4096, 1536, 1024);
  norm_rope_gate<<<dim3(1024), dim3(256), 0, stream>>>(qkv, x, qw, kw, gw, Qb, Kb, Vb, gate);
  transpose_v64<<<dim3(32, 8), dim3(256), 0, stream>>>(Vb, Vtb);
  attn_fwd_pair<<<dim3(16, 32), dim3(256), 0, stream>>>(Qb, Kb, Vtb, gate, attnh);
  gemm_nt<<<dim3(32, 8), dim3(256), 0, stream>>>(attnh, wb + (size_t)1536 * 1024, out, 4096, 1024, 1024);
}

// Round 7
// 149.272 us; speedup vs baseline: 2.2471x; 1.1028x over previous
//
#include <hip/hip_runtime.h>
#include <math.h>

typedef unsigned short u16;
typedef __bf16 bf16x8 __attribute__((ext_vector_type(8)));
typedef float f32x4 __attribute__((ext_vector_type(4)));
typedef unsigned short u16x8 __attribute__((ext_vector_type(8)));
typedef unsigned short u16x4 __attribute__((ext_vector_type(4)));

static __device__ __forceinline__ u16 f2bf(float f) {
  unsigned int u = __builtin_bit_cast(unsigned int, f);
  u = (u + 0x7FFFu + ((u >> 16) & 1u)) >> 16;
  return (u16)u;
}
static __device__ __forceinline__ float bf2f(u16 u) {
  unsigned int x = ((unsigned int)u) << 16;
  return __builtin_bit_cast(float, x);
}
static __device__ __forceinline__ u16 f2bfh(float f) {
  __bf16 b = (__bf16)f;
  return __builtin_bit_cast(u16, b);
}

// ---------------- f32 -> bf16 convert ----------------
__global__ __launch_bounds__(256) void cvt_bf16(const float* __restrict__ src, u16* __restrict__ dst, int n4) {
  int idx = blockIdx.x * 256 + threadIdx.x;
  if (idx < n4) {
    float4 v = ((const float4*)src)[idx];
    ushort4 r;
    r.x = f2bf(v.x); r.y = f2bf(v.y); r.z = f2bf(v.z); r.w = f2bf(v.w);
    ((ushort4*)dst)[idx] = r;
  }
}

// ---------------- plain bf16 NT GEMM: C = A * B^T, f32 out ----------------
__global__ __launch_bounds__(256) void gemm_nt(const u16* __restrict__ A, const u16* __restrict__ B,
                                               float* __restrict__ C, int M, int N, int K) {
  __shared__ __align__(16) u16 sA[128][40];
  __shared__ __align__(16) u16 sB[128][40];
  const int tid = threadIdx.x;
  const int w = tid >> 6, lane = tid & 63;
  const int m0 = blockIdx.x * 128, n0 = blockIdx.y * 128;
  const int wm = (w >> 1) * 64, wn = (w & 1) * 64;

  f32x4 acc[4][4] = {};
  const int srw = tid >> 1, sc0 = (tid & 1) * 16;

  for (int k0 = 0; k0 < K; k0 += 32) {
    {
      const u16* pa = A + (size_t)(m0 + srw) * K + k0 + sc0;
      const u16* pb = B + (size_t)(n0 + srw) * K + k0 + sc0;
      *(u16x8*)&sA[srw][sc0]     = *(const u16x8*)pa;
      *(u16x8*)&sA[srw][sc0 + 8] = *(const u16x8*)(pa + 8);
      *(u16x8*)&sB[srw][sc0]     = *(const u16x8*)pb;
      *(u16x8*)&sB[srw][sc0 + 8] = *(const u16x8*)(pb + 8);
    }
    __syncthreads();
    bf16x8 af[4], bfr[4];
#pragma unroll
    for (int m = 0; m < 4; ++m) af[m] = *(const bf16x8*)&sA[wm + m * 16 + (lane & 15)][(lane >> 4) * 8];
#pragma unroll
    for (int n = 0; n < 4; ++n) bfr[n] = *(const bf16x8*)&sB[wn + n * 16 + (lane & 15)][(lane >> 4) * 8];
#pragma unroll
    for (int m = 0; m < 4; ++m)
#pragma unroll
      for (int n = 0; n < 4; ++n)
        acc[m][n] = __builtin_amdgcn_mfma_f32_16x16x32_bf16(af[m], bfr[n], acc[m][n], 0, 0, 0);
    __syncthreads();
  }

#pragma unroll
  for (int m = 0; m < 4; ++m)
#pragma unroll
    for (int i = 0; i < 4; ++i) {
      int gr = m0 + wm + m * 16 + (lane >> 4) * 4 + i;
      float* crow = C + (size_t)gr * N + n0 + wn + (lane & 15);
#pragma unroll
      for (int n = 0; n < 4; ++n) crow[n * 16] = acc[m][n][i];
    }
}

// ---------------- RMSNorm + RoPE + V cast + gate ----------------
#define QSCALE 0.18033688011112042f
__global__ __launch_bounds__(256) void norm_rope_gate(const float* __restrict__ qkv, const float* __restrict__ x,
                                                      const float* __restrict__ qw, const float* __restrict__ kw,
                                                      const float* __restrict__ gw,
                                                      u16* __restrict__ Q, u16* __restrict__ Kd,
                                                      u16* __restrict__ V, float* __restrict__ gate) {
  const int t = blockIdx.x * 4 + (threadIdx.x >> 6);
  const int lane = threadIdx.x & 63;
  const int b = t >> 11, s = t & 2047;
  const float* base = qkv + (size_t)t * 1536;
  const int ri = lane >> 1;
  float sn, cs;
  sincosf((float)s * expf(-(float)ri * (9.21034037198f / 32.0f)), &sn, &cs);
  const float qwl = qw[lane], kwl = kw[lane];

  for (int hh = 0; hh < 16; ++hh) {
    float v = base[hh * 64 + lane];
    float ss = v * v;
#pragma unroll
    for (int off = 32; off >= 1; off >>= 1) ss += __shfl_xor(ss, off);
    float r = rsqrtf(ss * (1.0f / 64.0f) + 1.1920929e-7f);
    float xn = v * r * qwl;
    float p = __shfl_xor(xn, 1);
    float outv = ((lane & 1) == 0) ? (xn * cs - p * sn) : (xn * cs + p * sn);
    Q[((size_t)(b * 16 + hh) * 2048 + s) * 64 + lane] = f2bf(outv * QSCALE);
  }
  for (int hh = 0; hh < 4; ++hh) {
    float v = base[1024 + hh * 64 + lane];
    float ss = v * v;
#pragma unroll
    for (int off = 32; off >= 1; off >>= 1) ss += __shfl_xor(ss, off);
    float r = rsqrtf(ss * (1.0f / 64.0f) + 1.1920929e-7f);
    float xn = v * r * kwl;
    float p = __shfl_xor(xn, 1);
    float outv = ((lane & 1) == 0) ? (xn * cs - p * sn) : (xn * cs + p * sn);
    Kd[((size_t)(b * 4 + hh) * 2048 + s) * 64 + lane] = f2bf(outv);
    V[((size_t)(b * 4 + hh) * 2048 + s) * 64 + lane] = f2bf(base[1280 + hh * 64 + lane]);
  }
  if (lane < 16) {
    float g = 0.f;
#pragma unroll
    for (int j = 0; j < 12; ++j) g += x[(size_t)t * 1024 + j] * gw[lane * 12 + j];
    gate[(size_t)t * 16 + lane] = 1.0f / (1.0f + __expf(-g));
  }
}

// ---------------- V transpose: [bh][s][d] -> [bh][d][s] ----------------
__global__ __launch_bounds__(256) void transpose_v64(const u16* __restrict__ V, u16* __restrict__ Vt) {
  __shared__ __align__(16) u16 tile[64][72];
  const int st = blockIdx.x, bh = blockIdx.y;
  const u16* src = V + ((size_t)bh * 2048 + st * 64) * 64;
  u16* dst = Vt + (size_t)bh * 64 * 2048 + st * 64;
  const int t = threadIdx.x;
  const int r = t >> 2, c0 = (t & 3) * 16;
#pragma unroll
  for (int j = 0; j < 2; ++j)
    *(u16x8*)&tile[r][c0 + j * 8] = *(const u16x8*)&src[(size_t)r * 64 + c0 + j * 8];
  __syncthreads();
  u16 tmp[16];
#pragma unroll
  for (int j = 0; j < 16; ++j) tmp[j] = tile[c0 + j][r];
#pragma unroll
  for (int j = 0; j < 2; ++j)
    *(u16x8*)&dst[(size_t)r * 2048 + c0 + j * 8] = *(const u16x8*)&tmp[j * 8];
}

// ---------------- Flash attention, paired q-tiles + KV-parity split, no-max softmax ----
// grid (16, B*H, 2). Block (x, bh, z): q-tiles qiA=x, qiB=31-x; KV tiles t ≡ z (mod 2).
// Scores are pre-scaled into exp2 domain and bounded (|S'| ~ few sigma << 127), so
// softmax runs with fixed m=0: P = exp2(S'), l = sum P, no max tracking or rescale.
// Partials (unnormalized acc bf16, l f32) are combined by attn_combine.
__global__ __launch_bounds__(256) void attn_fwd_pair(const u16* __restrict__ Q, const u16* __restrict__ Kg,
                                                     const u16* __restrict__ Vt,
                                                     u16* __restrict__ accP, float* __restrict__ lP) {
  __shared__ __align__(16) u16 sK[2][64][72];    // K[kv][d], double-buffered
  __shared__ __align__(16) u16 sV[2][64][72];    // Vt[d][kv]
  __shared__ __align__(16) u16 sP[4][16][68];    // per-wave P buffer (streams serialized)

  const int tid = threadIdx.x;
  const int w = tid >> 6, lane = tid & 63;
  const int l15 = lane & 15, lg = lane >> 4;
  const int qiA = blockIdx.x;          // 0..15
  const int qiB = 31 - qiA;            // 31..16
  const int z = blockIdx.z;
  const int bh = blockIdx.y, b = bh >> 4, h = bh & 15, kvh = h >> 2;

  const u16* Qp = Q + (size_t)(b * 16 + h) * 2048 * 64;
  const u16* Kp = Kg + (size_t)(b * 4 + kvh) * 2048 * 64;
  const u16* Vp = Vt + (size_t)(b * 4 + kvh) * 64 * 2048;

  const int q0s[2] = {qiA * 64, qiB * 64};
  bf16x8 qa[2][2];
#pragma unroll
  for (int s = 0; s < 2; ++s) {
    const u16* qrow = Qp + (size_t)(q0s[s] + w * 16 + l15) * 64 + lg * 8;
    qa[s][0] = *(const bf16x8*)qrow;
    qa[s][1] = *(const bf16x8*)(qrow + 32);
  }

  f32x4 acc[2][4] = {};
  float l_run[2][4] = {};

  const int srw = tid >> 2, sc0 = (tid & 3) * 16;
  const u16* kgp = Kp + (size_t)srw * 64 + sc0;
  const u16* vgp = Vp + (size_t)srw * 2048 + sc0;

  // prologue: stage tile z into buffer 0
  u16x8 kr0 = *(const u16x8*)(kgp + (size_t)z * 64 * 64), kr1 = *(const u16x8*)(kgp + (size_t)z * 64 * 64 + 8);
  u16x8 vr0 = *(const u16x8*)(vgp + z * 64),              vr1 = *(const u16x8*)(vgp + z * 64 + 8);
  *(u16x8*)&sK[0][srw][sc0] = kr0; *(u16x8*)&sK[0][srw][sc0 + 8] = kr1;
  *(u16x8*)&sV[0][srw][sc0] = vr0; *(u16x8*)&sV[0][srw][sc0 + 8] = vr1;
  __syncthreads();

  for (int t = z; t <= qiB; t += 2) {
    const int buf = (t >> 1) & 1;

    // T14: issue tile t+2's global loads now; consume after compute.
    if (t + 2 <= qiB) {
      const u16* kg = kgp + (size_t)(t + 2) * 64 * 64;
      const u16* vg = vgp + (t + 2) * 64;
      kr0 = *(const u16x8*)kg; kr1 = *(const u16x8*)(kg + 8);
      vr0 = *(const u16x8*)vg; vr1 = *(const u16x8*)(vg + 8);
    }

    // shared K / V fragments (read once, used by both streams)
    bf16x8 kf[4][2], vf[4][2];
#pragma unroll
    for (int ct = 0; ct < 4; ++ct) {
      const int r = ct * 16 + l15;
      kf[ct][0] = *(const bf16x8*)&sK[buf][r][lg * 8];
      kf[ct][1] = *(const bf16x8*)&sK[buf][r][32 + lg * 8];
      vf[ct][0] = *(const bf16x8*)&sV[buf][r][lg * 8];
      vf[ct][1] = *(const bf16x8*)&sV[buf][r][32 + lg * 8];
    }

#pragma unroll
    for (int s = 0; s < 2; ++s) {
      if (s == 0 && t > qiA) continue;     // stream A done (uniform branch)
      const int diag = s ? qiB : qiA;

      f32x4 sc[4];
#pragma unroll
      for (int ct = 0; ct < 4; ++ct) {
        f32x4 s4 = {};
        s4 = __builtin_amdgcn_mfma_f32_16x16x32_bf16(qa[s][0], kf[ct][0], s4, 0, 0, 0);
        s4 = __builtin_amdgcn_mfma_f32_16x16x32_bf16(qa[s][1], kf[ct][1], s4, 0, 0, 0);
        sc[ct] = s4;
      }

      if (t == diag) {
        const int colb = t * 64 + l15;
        const int rowb = q0s[s] + w * 16 + lg * 4;
#pragma unroll
        for (int ct = 0; ct < 4; ++ct)
#pragma unroll
          for (int i = 0; i < 4; ++i)
            sc[ct][i] = (colb + ct * 16 <= rowb + i) ? sc[ct][i] : -1e30f;
      }

      // no-max softmax: P = exp2(S'), accumulate l from the bf16-rounded P
      u16 pb[4][4];
      float rs[4] = {0.f, 0.f, 0.f, 0.f};
#pragma unroll
      for (int ct = 0; ct < 4; ++ct)
#pragma unroll
        for (int i = 0; i < 4; ++i) {
          float p = exp2f(sc[ct][i]);
          u16 pbits = f2bfh(p);
          pb[ct][i] = pbits;
          rs[i] += bf2f(pbits);
        }
#pragma unroll
      for (int i = 0; i < 4; ++i) l_run[s][i] += rs[i];

      // P -> per-wave LDS (wave-internal; DS ops are in-order per wave, no barrier)
#pragma unroll
      for (int ct = 0; ct < 4; ++ct)
#pragma unroll
        for (int i = 0; i < 4; ++i)
          sP[w][lg * 4 + i][ct * 16 + l15] = pb[ct][i];

      u16x4 p00 = *(const u16x4*)&sP[w][l15][lg * 8];
      u16x4 p01 = *(const u16x4*)&sP[w][l15][lg * 8 + 4];
      u16x4 p10 = *(const u16x4*)&sP[w][l15][32 + lg * 8];
      u16x4 p11 = *(const u16x4*)&sP[w][l15][32 + lg * 8 + 4];
      bf16x8 pa0 = __builtin_bit_cast(bf16x8, __builtin_shufflevector(p00, p01, 0, 1, 2, 3, 4, 5, 6, 7));
      bf16x8 pa1 = __builtin_bit_cast(bf16x8, __builtin_shufflevector(p10, p11, 0, 1, 2, 3, 4, 5, 6, 7));

#pragma unroll
      for (int n = 0; n < 4; ++n) {
        acc[s][n] = __builtin_amdgcn_mfma_f32_16x16x32_bf16(pa0, vf[n][0], acc[s][n], 0, 0, 0);
        acc[s][n] = __builtin_amdgcn_mfma_f32_16x16x32_bf16(pa1, vf[n][1], acc[s][n], 0, 0, 0);
      }
    }

    if (t + 2 <= qiB) {
      *(u16x8*)&sK[buf ^ 1][srw][sc0] = kr0; *(u16x8*)&sK[buf ^ 1][srw][sc0 + 8] = kr1;
      *(u16x8*)&sV[buf ^ 1][srw][sc0] = vr0; *(u16x8*)&sV[buf ^ 1][srw][sc0 + 8] = vr1;
    }
    __syncthreads();
  }

  // epilogue: reduce l across the 16-lane column group; write unnormalized partials.
  // Writes BOTH streams unconditionally (zero-partials included) so ws poison is cleared.
#pragma unroll
  for (int s = 0; s < 2; ++s) {
#pragma unroll
    for (int off = 8; off >= 1; off >>= 1)
#pragma unroll
      for (int i = 0; i < 4; ++i) l_run[s][i] += __shfl_xor(l_run[s][i], off);
#pragma unroll
    for (int i = 0; i < 4; ++i) {
      int srowg = q0s[s] + w * 16 + lg * 4 + i;
      size_t rowbase = (size_t)z * 4096 + b * 2048 + srowg;
      if (l15 == 0) lP[rowbase * 16 + h] = l_run[s][i];
      u16* orow = accP + rowbase * 1024 + h * 64 + l15;
#pragma unroll
      for (int n = 0; n < 4; ++n) orow[n * 16] = f2bfh(acc[s][n][i]);
    }
  }
}

// ---------------- combine KV-split partials: O = (a0+a1)/(l0+l1) * gate ----------------
__global__ __launch_bounds__(256) void attn_combine(const u16* __restrict__ accP, const float* __restrict__ lP,
                                                    const float* __restrict__ gate, u16* __restrict__ attnh) {
  const size_t e = ((size_t)blockIdx.x * 256 + threadIdx.x) * 8;
  const int token = (int)(e >> 10);
  const int h = (int)((e >> 6) & 15);
  u16x8 a0 = *(const u16x8*)(accP + e);
  u16x8 a1 = *(const u16x8*)(accP + ((size_t)4096 << 10) + e);
  float l0 = lP[(size_t)token * 16 + h];
  float l1 = lP[(size_t)4096 * 16 + (size_t)token * 16 + h];
  float g = gate[(size_t)token * 16 + h] / (l0 + l1);
  u16x8 o;
#pragma unroll
  for (int j = 0; j < 8; ++j) o[j] = f2bfh((bf2f(a0[j]) + bf2f(a1[j])) * g);
  *(u16x8*)(attnh + e) = o;
}

// ---------------- launch ----------------
extern "C" void kernel_launch(void* const* d_in, const int* in_sizes, int n_in,
                              void* d_out, int out_size, void* d_ws, size_t ws_size,
                              hipStream_t stream) {
  const float* x  = (const float*)d_in[0];
  const float* Wf = (const float*)d_in[1];
  const float* qw = (const float*)d_in[2];
  const float* kw = (const float*)d_in[3];
  const float* gw = (const float*)d_in[4];
  float* out = (float*)d_out;

  char* ws = (char*)d_ws;
  size_t off = 0;
  auto alloc = [&](size_t bytes) { void* p = ws + off; off += (bytes + 255) & ~(size_t)255; return p; };

  u16*   xb   = (u16*)alloc((size_t)4096 * 1024 * 2);
  u16*   wb   = (u16*)alloc((size_t)2560 * 1024 * 2);
  float* qkv  = (float*)alloc((size_t)4096 * 1536 * 4);
  u16*   Qb   = (u16*)alloc((size_t)2 * 16 * 2048 * 64 * 2);
  u16*   Kb   = (u16*)alloc((size_t)2 * 4 * 2048 * 64 * 2);
  u16*   Vb   = (u16*)alloc((size_t)2 * 4 * 2048 * 64 * 2);
  u16*   Vtb  = (u16*)alloc((size_t)2 * 4 * 2048 * 64 * 2);
  float* gate = (float*)alloc((size_t)2 * 2048 * 16 * 4);
  float* lP   = (float*)alloc((size_t)2 * 4096 * 16 * 4);
  // partial acc (16 MB) aliases qkv (24 MB, dead after norm_rope_gate);
  // attnh (8 MB) aliases xb (dead after the QKV GEMM).
  u16* accP  = (u16*)qkv;
  u16* attnh = xb;

  cvt_bf16<<<dim3(4096), dim3(256), 0, stream>>>(x, xb, 4096 * 1024 / 4);
  cvt_bf16<<<dim3(2560), dim3(256), 0, stream>>>(Wf, wb, 2560 * 1024 / 4);
  gemm_nt<<<dim3(32, 12), dim3(256), 0, stream>>>(xb, wb, qkv, 4096, 1536, 1024);
  norm_rope_gate<<<dim3(1024), dim3(256), 0, stream>>>(qkv, x, qw, kw, gw, Qb, Kb, Vb, gate);
  transpose_v64<<<dim3(32, 8), dim3(256), 0, stream>>>(Vb, Vtb);
  attn_fwd_pair<<<dim3(16, 32, 2), dim3(256), 0, stream>>>(Qb, Kb, Vtb, accP, lP);
  attn_combine<<<dim3(2048), dim3(256), 0, stream>>>(accP, lP, gate, attnh);
  gemm_nt<<<dim3(32, 8), dim3(256), 0, stream>>>(attnh, wb + (size_t)1536 * 1024, out, 4096, 1024, 1024);
}

// Round 8
// 139.605 us; speedup vs baseline: 2.4027x; 1.0693x over previous
//
#include <hip/hip_runtime.h>
#include <math.h>

typedef unsigned short u16;
typedef unsigned int u32;
typedef __bf16 bf16x8 __attribute__((ext_vector_type(8)));
typedef float f32x4 __attribute__((ext_vector_type(4)));
typedef unsigned short u16x8 __attribute__((ext_vector_type(8)));
typedef unsigned short u16x4 __attribute__((ext_vector_type(4)));
typedef unsigned int u32x2 __attribute__((ext_vector_type(2)));

static __device__ __forceinline__ u16 f2bf(float f) {
  unsigned int u = __builtin_bit_cast(unsigned int, f);
  u = (u + 0x7FFFu + ((u >> 16) & 1u)) >> 16;
  return (u16)u;
}
static __device__ __forceinline__ float bf2f(u16 u) {
  unsigned int x = ((unsigned int)u) << 16;
  return __builtin_bit_cast(float, x);
}
static __device__ __forceinline__ u16 f2bfh(float f) {
  __bf16 b = (__bf16)f;
  return __builtin_bit_cast(u16, b);
}
static __device__ __forceinline__ void gll16(const u16* g, u16* l) {
  __builtin_amdgcn_global_load_lds((const __attribute__((address_space(1))) u32*)g,
                                   (__attribute__((address_space(3))) u32*)l, 16, 0, 0);
}

// ---------------- f32 -> bf16 convert ----------------
__global__ __launch_bounds__(256) void cvt_bf16(const float* __restrict__ src, u16* __restrict__ dst, int n4) {
  int idx = blockIdx.x * 256 + threadIdx.x;
  if (idx < n4) {
    float4 v = ((const float4*)src)[idx];
    ushort4 r;
    r.x = f2bf(v.x); r.y = f2bf(v.y); r.z = f2bf(v.z); r.w = f2bf(v.w);
    ((ushort4*)dst)[idx] = r;
  }
}

// ---------------- bf16 NT GEMM, m97 structure: gll16 staging, linear LDS + swizzled src ----
// 128x128 tile, BK=32, 256 threads (4 waves, each 64x64).
__global__ __launch_bounds__(256) void gemm_nt(const u16* __restrict__ A, const u16* __restrict__ B,
                                               float* __restrict__ C, int M, int N, int K) {
  __shared__ __align__(16) u16 sA[128 * 32];
  __shared__ __align__(16) u16 sB[128 * 32];
  const int tid = threadIdx.x;
  const int w = tid >> 6, lane = tid & 63, l15 = lane & 15;
  const int m0 = blockIdx.x * 128, n0 = blockIdx.y * 128;
  const int wm = (w >> 1) * 64, wn = (w & 1) * 64;

  f32x4 acc[4][4] = {};

  // staging: LDS byte p = i*4096 + w*1024 + lane*16 (linear dest; source pre-swizzled)
  const int pb0 = w * 1024 + lane * 16;
  int srow[2], scol[2];
#pragma unroll
  for (int i = 0; i < 2; ++i) {
    int p = pb0 + i * 4096;
    int row = p >> 6, oo = p & 63;
    int ol = oo ^ (((row >> 1) & 3) << 4);
    srow[i] = row; scol[i] = ol >> 1;
  }
  // fragment read byte offsets (same swizzle)
  int aoff[4], boff[4];
  const int kb = (lane >> 4) * 16;
#pragma unroll
  for (int m = 0; m < 4; ++m) {
    int r = wm + m * 16 + l15;
    aoff[m] = r * 64 + (kb ^ (((r >> 1) & 3) << 4));
  }
#pragma unroll
  for (int n = 0; n < 4; ++n) {
    int r = wn + n * 16 + l15;
    boff[n] = r * 64 + (kb ^ (((r >> 1) & 3) << 4));
  }

  for (int k0 = 0; k0 < K; k0 += 32) {
#pragma unroll
    for (int i = 0; i < 2; ++i) {
      int p = pb0 + i * 4096;
      gll16(A + (size_t)(m0 + srow[i]) * K + k0 + scol[i], (u16*)((char*)sA + p));
      gll16(B + (size_t)(n0 + srow[i]) * K + k0 + scol[i], (u16*)((char*)sB + p));
    }
    __syncthreads();
    bf16x8 af[4], bfr[4];
#pragma unroll
    for (int m = 0; m < 4; ++m) af[m] = *(const bf16x8*)((const char*)sA + aoff[m]);
#pragma unroll
    for (int n = 0; n < 4; ++n) bfr[n] = *(const bf16x8*)((const char*)sB + boff[n]);
#pragma unroll
    for (int m = 0; m < 4; ++m)
#pragma unroll
      for (int n = 0; n < 4; ++n)
        acc[m][n] = __builtin_amdgcn_mfma_f32_16x16x32_bf16(af[m], bfr[n], acc[m][n], 0, 0, 0);
    __syncthreads();
  }

#pragma unroll
  for (int m = 0; m < 4; ++m)
#pragma unroll
    for (int i = 0; i < 4; ++i) {
      int gr = m0 + wm + m * 16 + (lane >> 4) * 4 + i;
      float* crow = C + (size_t)gr * N + n0 + wn + l15;
#pragma unroll
      for (int n = 0; n < 4; ++n) crow[n * 16] = acc[m][n][i];
    }
}

// ---------------- RMSNorm + RoPE + V cast + gate ----------------
#define QSCALE 0.18033688011112042f
__global__ __launch_bounds__(256) void norm_rope_gate(const float* __restrict__ qkv, const float* __restrict__ x,
                                                      const float* __restrict__ qw, const float* __restrict__ kw,
                                                      const float* __restrict__ gw,
                                                      u16* __restrict__ Q, u16* __restrict__ Kd,
                                                      u16* __restrict__ V, float* __restrict__ gate) {
  const int t = blockIdx.x * 4 + (threadIdx.x >> 6);
  const int lane = threadIdx.x & 63;
  const int b = t >> 11, s = t & 2047;
  const float* base = qkv + (size_t)t * 1536;
  const int ri = lane >> 1;
  float sn, cs;
  sincosf((float)s * expf(-(float)ri * (9.21034037198f / 32.0f)), &sn, &cs);
  const float qwl = qw[lane], kwl = kw[lane];

  for (int hh = 0; hh < 16; ++hh) {
    float v = base[hh * 64 + lane];
    float ss = v * v;
#pragma unroll
    for (int off = 32; off >= 1; off >>= 1) ss += __shfl_xor(ss, off);
    float r = rsqrtf(ss * (1.0f / 64.0f) + 1.1920929e-7f);
    float xn = v * r * qwl;
    float p = __shfl_xor(xn, 1);
    float outv = ((lane & 1) == 0) ? (xn * cs - p * sn) : (xn * cs + p * sn);
    Q[((size_t)(b * 16 + hh) * 2048 + s) * 64 + lane] = f2bf(outv * QSCALE);
  }
  for (int hh = 0; hh < 4; ++hh) {
    float v = base[1024 + hh * 64 + lane];
    float ss = v * v;
#pragma unroll
    for (int off = 32; off >= 1; off >>= 1) ss += __shfl_xor(ss, off);
    float r = rsqrtf(ss * (1.0f / 64.0f) + 1.1920929e-7f);
    float xn = v * r * kwl;
    float p = __shfl_xor(xn, 1);
    float outv = ((lane & 1) == 0) ? (xn * cs - p * sn) : (xn * cs + p * sn);
    Kd[((size_t)(b * 4 + hh) * 2048 + s) * 64 + lane] = f2bf(outv);
    V[((size_t)(b * 4 + hh) * 2048 + s) * 64 + lane] = f2bf(base[1280 + hh * 64 + lane]);
  }
  if (lane < 16) {
    float g = 0.f;
#pragma unroll
    for (int j = 0; j < 12; ++j) g += x[(size_t)t * 1024 + j] * gw[lane * 12 + j];
    gate[(size_t)t * 16 + lane] = 1.0f / (1.0f + __expf(-g));
  }
}

// ---------------- V transpose: [bh][s][d] -> [bh][d][s] ----------------
__global__ __launch_bounds__(256) void transpose_v64(const u16* __restrict__ V, u16* __restrict__ Vt) {
  __shared__ __align__(16) u16 tile[64][72];
  const int st = blockIdx.x, bh = blockIdx.y;
  const u16* src = V + ((size_t)bh * 2048 + st * 64) * 64;
  u16* dst = Vt + (size_t)bh * 64 * 2048 + st * 64;
  const int t = threadIdx.x;
  const int r = t >> 2, c0 = (t & 3) * 16;
#pragma unroll
  for (int j = 0; j < 2; ++j)
    *(u16x8*)&tile[r][c0 + j * 8] = *(const u16x8*)&src[(size_t)r * 64 + c0 + j * 8];
  __syncthreads();
  u16 tmp[16];
#pragma unroll
  for (int j = 0; j < 16; ++j) tmp[j] = tile[c0 + j][r];
#pragma unroll
  for (int j = 0; j < 2; ++j)
    *(u16x8*)&dst[(size_t)r * 2048 + c0 + j * 8] = *(const u16x8*)&tmp[j * 8];
}

// ---------------- Flash attention: paired q-tiles + KV-parity split, swapped QK^T ------
// grid (16, B*H, 2). Block (x,bh,z): q-tiles qiA=x, qiB=31-x; KV tiles t ≡ z (mod 2).
// Swapped QK^T (mfma(K,Q) = S^T): lane owns P-row q=lane&15, kv=ct*16+lg*4+i. P packed
// to u32 pairs -> 4 ds_write_b64/tile-stream; l is one scalar/lane, unrounded, reduced
// only at epilogue. No-max softmax (scores pre-scaled into exp2 domain, |S'| << 127).
__global__ __launch_bounds__(256) void attn_fwd_pair(const u16* __restrict__ Q, const u16* __restrict__ Kg,
                                                     const u16* __restrict__ Vt,
                                                     u16* __restrict__ accP, float* __restrict__ lP) {
  __shared__ __align__(16) u16 sK[2][64][72];   // K[kv][d], double-buffered
  __shared__ __align__(16) u16 sV[2][64][72];   // Vt[d][kv]
  __shared__ __align__(16) u16 sP[4][16][68];   // per-wave P[q][kv] (streams serialized)

  const int tid = threadIdx.x;
  const int w = tid >> 6, lane = tid & 63;
  const int l15 = lane & 15, lg = lane >> 4;
  const int qiA = blockIdx.x;          // 0..15
  const int qiB = 31 - qiA;            // 31..16
  const int z = blockIdx.z;
  const int bh = blockIdx.y, b = bh >> 4, h = bh & 15, kvh = h >> 2;

  const u16* Qp = Q + (size_t)(b * 16 + h) * 2048 * 64;
  const u16* Kp = Kg + (size_t)(b * 4 + kvh) * 2048 * 64;
  const u16* Vp = Vt + (size_t)(b * 4 + kvh) * 64 * 2048;

  const int q0s[2] = {qiA * 64, qiB * 64};
  bf16x8 qa[2][2];
#pragma unroll
  for (int s = 0; s < 2; ++s) {
    const u16* qrow = Qp + (size_t)(q0s[s] + w * 16 + l15) * 64 + lg * 8;
    qa[s][0] = *(const bf16x8*)qrow;
    qa[s][1] = *(const bf16x8*)(qrow + 32);
  }

  f32x4 acc[2][4] = {};
  float l_s[2] = {0.f, 0.f};

  const int srw = tid >> 2, sc0 = (tid & 3) * 16;
  const u16* kgp = Kp + (size_t)srw * 64 + sc0;
  const u16* vgp = Vp + (size_t)srw * 2048 + sc0;

  // prologue: stage tile z into buffer 0
  u16x8 kr0 = *(const u16x8*)(kgp + (size_t)z * 64 * 64), kr1 = *(const u16x8*)(kgp + (size_t)z * 64 * 64 + 8);
  u16x8 vr0 = *(const u16x8*)(vgp + z * 64),              vr1 = *(const u16x8*)(vgp + z * 64 + 8);
  *(u16x8*)&sK[0][srw][sc0] = kr0; *(u16x8*)&sK[0][srw][sc0 + 8] = kr1;
  *(u16x8*)&sV[0][srw][sc0] = vr0; *(u16x8*)&sV[0][srw][sc0 + 8] = vr1;
  __syncthreads();

  for (int t = z; t <= qiB; t += 2) {
    const int buf = (t >> 1) & 1;

    // T14: issue tile t+2's global loads now; consume after compute.
    if (t + 2 <= qiB) {
      const u16* kg = kgp + (size_t)(t + 2) * 64 * 64;
      const u16* vg = vgp + (t + 2) * 64;
      kr0 = *(const u16x8*)kg; kr1 = *(const u16x8*)(kg + 8);
      vr0 = *(const u16x8*)vg; vr1 = *(const u16x8*)(vg + 8);
    }

    // shared K / V fragments (read once, used by both streams)
    bf16x8 kf[4][2], vf[4][2];
#pragma unroll
    for (int ct = 0; ct < 4; ++ct) {
      const int r = ct * 16 + l15;
      kf[ct][0] = *(const bf16x8*)&sK[buf][r][lg * 8];
      kf[ct][1] = *(const bf16x8*)&sK[buf][r][32 + lg * 8];
      vf[ct][0] = *(const bf16x8*)&sV[buf][r][lg * 8];
      vf[ct][1] = *(const bf16x8*)&sV[buf][r][32 + lg * 8];
    }

#pragma unroll
    for (int s = 0; s < 2; ++s) {
      if (s == 0 && t > qiA) continue;     // stream A done (uniform branch)
      const int diag = s ? qiB : qiA;

      // S^T = K Q^T: lane holds S[kv=ct*16+lg*4+i][q=l15]
      f32x4 st[4];
#pragma unroll
      for (int ct = 0; ct < 4; ++ct) {
        f32x4 s4 = {};
        s4 = __builtin_amdgcn_mfma_f32_16x16x32_bf16(kf[ct][0], qa[s][0], s4, 0, 0, 0);
        s4 = __builtin_amdgcn_mfma_f32_16x16x32_bf16(kf[ct][1], qa[s][1], s4, 0, 0, 0);
        st[ct] = s4;
      }

      if (t == diag) {
        // causal mask within diagonal tile: kv_local <= q_local
        const int ql = w * 16 + l15;
#pragma unroll
        for (int ct = 0; ct < 4; ++ct)
#pragma unroll
          for (int i = 0; i < 4; ++i)
            st[ct][i] = (ct * 16 + lg * 4 + i <= ql) ? st[ct][i] : -1e30f;
      }

      // P = exp2(S'), pack pairs, accumulate per-lane row-sum (q=l15)
      float ls = 0.f;
#pragma unroll
      for (int ct = 0; ct < 4; ++ct) {
        float p0 = exp2f(st[ct][0]), p1 = exp2f(st[ct][1]);
        float p2 = exp2f(st[ct][2]), p3 = exp2f(st[ct][3]);
        ls += (p0 + p1) + (p2 + p3);
        u32 lo = (u32)f2bfh(p0) | ((u32)f2bfh(p1) << 16);
        u32 hi = (u32)f2bfh(p2) | ((u32)f2bfh(p3) << 16);
        *(u32x2*)&sP[w][l15][ct * 16 + lg * 4] = (u32x2){lo, hi};
      }
      l_s[s] += ls;

      // read P as A-fragments (wave-internal; compiler-ordered lgkmcnt)
      u16x4 p00 = *(const u16x4*)&sP[w][l15][lg * 8];
      u16x4 p01 = *(const u16x4*)&sP[w][l15][lg * 8 + 4];
      u16x4 p10 = *(const u16x4*)&sP[w][l15][32 + lg * 8];
      u16x4 p11 = *(const u16x4*)&sP[w][l15][32 + lg * 8 + 4];
      bf16x8 pa0 = __builtin_bit_cast(bf16x8, __builtin_shufflevector(p00, p01, 0, 1, 2, 3, 4, 5, 6, 7));
      bf16x8 pa1 = __builtin_bit_cast(bf16x8, __builtin_shufflevector(p10, p11, 0, 1, 2, 3, 4, 5, 6, 7));

#pragma unroll
      for (int n = 0; n < 4; ++n) {
        acc[s][n] = __builtin_amdgcn_mfma_f32_16x16x32_bf16(pa0, vf[n][0], acc[s][n], 0, 0, 0);
        acc[s][n] = __builtin_amdgcn_mfma_f32_16x16x32_bf16(pa1, vf[n][1], acc[s][n], 0, 0, 0);
      }
    }

    if (t + 2 <= qiB) {
      *(u16x8*)&sK[buf ^ 1][srw][sc0] = kr0; *(u16x8*)&sK[buf ^ 1][srw][sc0 + 8] = kr1;
      *(u16x8*)&sV[buf ^ 1][srw][sc0] = vr0; *(u16x8*)&sV[buf ^ 1][srw][sc0 + 8] = vr1;
    }
    __syncthreads();
  }

  // epilogue: reduce l across lg-groups (lanes l15, l15+16, +32, +48), write partials.
#pragma unroll
  for (int s = 0; s < 2; ++s) {
    float lv = l_s[s];
    lv += __shfl_xor(lv, 16);
    lv += __shfl_xor(lv, 32);
    if (lg == 0) {
      int qrow = q0s[s] + w * 16 + l15;
      lP[((size_t)z * 4096 + b * 2048 + qrow) * 16 + h] = lv;
    }
#pragma unroll
    for (int i = 0; i < 4; ++i) {
      int srowg = q0s[s] + w * 16 + lg * 4 + i;
      size_t rowbase = (size_t)z * 4096 + b * 2048 + srowg;
      u16* orow = accP + rowbase * 1024 + h * 64 + l15;
#pragma unroll
      for (int n = 0; n < 4; ++n) orow[n * 16] = f2bfh(acc[s][n][i]);
    }
  }
}

// ---------------- combine KV-split partials: O = (a0+a1)/(l0+l1) * gate ----------------
__global__ __launch_bounds__(256) void attn_combine(const u16* __restrict__ accP, const float* __restrict__ lP,
                                                    const float* __restrict__ gate, u16* __restrict__ attnh) {
  const size_t e = ((size_t)blockIdx.x * 256 + threadIdx.x) * 8;
  const int token = (int)(e >> 10);
  const int h = (int)((e >> 6) & 15);
  u16x8 a0 = *(const u16x8*)(accP + e);
  u16x8 a1 = *(const u16x8*)(accP + ((size_t)4096 << 10) + e);
  float l0 = lP[(size_t)token * 16 + h];
  float l1 = lP[(size_t)4096 * 16 + (size_t)token * 16 + h];
  float g = gate[(size_t)token * 16 + h] / (l0 + l1);
  u16x8 o;
#pragma unroll
  for (int j = 0; j < 8; ++j) o[j] = f2bfh((bf2f(a0[j]) + bf2f(a1[j])) * g);
  *(u16x8*)(attnh + e) = o;
}

// ---------------- launch ----------------
extern "C" void kernel_launch(void* const* d_in, const int* in_sizes, int n_in,
                              void* d_out, int out_size, void* d_ws, size_t ws_size,
                              hipStream_t stream) {
  const float* x  = (const float*)d_in[0];
  const float* Wf = (const float*)d_in[1];
  const float* qw = (const float*)d_in[2];
  const float* kw = (const float*)d_in[3];
  const float* gw = (const float*)d_in[4];
  float* out = (float*)d_out;

  char* ws = (char*)d_ws;
  size_t off = 0;
  auto alloc = [&](size_t bytes) { void* p = ws + off; off += (bytes + 255) & ~(size_t)255; return p; };

  u16*   xb   = (u16*)alloc((size_t)4096 * 1024 * 2);
  u16*   wb   = (u16*)alloc((size_t)2560 * 1024 * 2);
  float* qkv  = (float*)alloc((size_t)4096 * 1536 * 4);
  u16*   Qb   = (u16*)alloc((size_t)2 * 16 * 2048 * 64 * 2);
  u16*   Kb   = (u16*)alloc((size_t)2 * 4 * 2048 * 64 * 2);
  u16*   Vb   = (u16*)alloc((size_t)2 * 4 * 2048 * 64 * 2);
  u16*   Vtb  = (u16*)alloc((size_t)2 * 4 * 2048 * 64 * 2);
  float* gate = (float*)alloc((size_t)2 * 2048 * 16 * 4);
  float* lP   = (float*)alloc((size_t)2 * 4096 * 16 * 4);
  // partial acc (16 MB) aliases qkv (24 MB, dead after norm_rope_gate);
  // attnh (8 MB) aliases xb (dead after the QKV GEMM).
  u16* accP  = (u16*)qkv;
  u16* attnh = xb;

  cvt_bf16<<<dim3(4096), dim3(256), 0, stream>>>(x, xb, 4096 * 1024 / 4);
  cvt_bf16<<<dim3(2560), dim3(256), 0, stream>>>(Wf, wb, 2560 * 1024 / 4);
  gemm_nt<<<dim3(32, 12), dim3(256), 0, stream>>>(xb, wb, qkv, 4096, 1536, 1024);
  norm_rope_gate<<<dim3(1024), dim3(256), 0, stream>>>(qkv, x, qw, kw, gw, Qb, Kb, Vb, gate);
  transpose_v64<<<dim3(32, 8), dim3(256), 0, stream>>>(Vb, Vtb);
  attn_fwd_pair<<<dim3(16, 32, 2), dim3(256), 0, stream>>>(Qb, Kb, Vtb, accP, lP);
  attn_combine<<<dim3(2048), dim3(256), 0, stream>>>(accP, lP, gate, attnh);
  gemm_nt<<<dim3(32, 8), dim3(256), 0, stream>>>(attnh, wb + (size_t)1536 * 1024, out, 4096, 1024, 1024);
}

// Round 9
// 135.171 us; speedup vs baseline: 2.4816x; 1.0328x over previous
//
#include <hip/hip_runtime.h>
#include <math.h>

typedef unsigned short u16;
typedef unsigned int u32;
typedef __bf16 bf16x8 __attribute__((ext_vector_type(8)));
typedef float f32x4 __attribute__((ext_vector_type(4)));
typedef unsigned short u16x8 __attribute__((ext_vector_type(8)));
typedef unsigned int u32x2 __attribute__((ext_vector_type(2)));

static __device__ __forceinline__ u16 f2bf(float f) {
  unsigned int u = __builtin_bit_cast(unsigned int, f);
  u = (u + 0x7FFFu + ((u >> 16) & 1u)) >> 16;
  return (u16)u;
}
static __device__ __forceinline__ float bf2f(u16 u) {
  unsigned int x = ((unsigned int)u) << 16;
  return __builtin_bit_cast(float, x);
}
static __device__ __forceinline__ u16 f2bfh(float f) {
  __bf16 b = (__bf16)f;
  return __builtin_bit_cast(u16, b);
}
static __device__ __forceinline__ void gll16(const u16* g, u16* l) {
  __builtin_amdgcn_global_load_lds((const __attribute__((address_space(1))) u32*)g,
                                   (__attribute__((address_space(3))) u32*)l, 16, 0, 0);
}

// ---------------- fused f32 -> bf16 convert for two buffers ----------------
__global__ __launch_bounds__(256) void cvt2_bf16(const float* __restrict__ a, u16* __restrict__ da, int n4a,
                                                 const float* __restrict__ b, u16* __restrict__ db, int n4b) {
  int idx = blockIdx.x * 256 + threadIdx.x;
  const float* src; u16* dst; int i;
  if (idx < n4a) { src = a; dst = da; i = idx; }
  else { i = idx - n4a; if (i >= n4b) return; src = b; dst = db; }
  float4 v = ((const float4*)src)[i];
  ushort4 r;
  r.x = f2bf(v.x); r.y = f2bf(v.y); r.z = f2bf(v.z); r.w = f2bf(v.w);
  ((ushort4*)dst)[i] = r;
}

// ---------------- bf16 NT GEMM, m97 structure: gll16 staging, linear LDS + swizzled src ----
// 128x128 tile, BK=32, 256 threads (4 waves, each 64x64).
__global__ __launch_bounds__(256) void gemm_nt(const u16* __restrict__ A, const u16* __restrict__ B,
                                               float* __restrict__ C, int M, int N, int K) {
  __shared__ __align__(16) u16 sA[128 * 32];
  __shared__ __align__(16) u16 sB[128 * 32];
  const int tid = threadIdx.x;
  const int w = tid >> 6, lane = tid & 63, l15 = lane & 15;
  const int m0 = blockIdx.x * 128, n0 = blockIdx.y * 128;
  const int wm = (w >> 1) * 64, wn = (w & 1) * 64;

  f32x4 acc[4][4] = {};

  const int pb0 = w * 1024 + lane * 16;
  int srow[2], scol[2];
#pragma unroll
  for (int i = 0; i < 2; ++i) {
    int p = pb0 + i * 4096;
    int row = p >> 6, oo = p & 63;
    int ol = oo ^ (((row >> 1) & 3) << 4);
    srow[i] = row; scol[i] = ol >> 1;
  }
  int aoff[4], boff[4];
  const int kb = (lane >> 4) * 16;
#pragma unroll
  for (int m = 0; m < 4; ++m) {
    int r = wm + m * 16 + l15;
    aoff[m] = r * 64 + (kb ^ (((r >> 1) & 3) << 4));
  }
#pragma unroll
  for (int n = 0; n < 4; ++n) {
    int r = wn + n * 16 + l15;
    boff[n] = r * 64 + (kb ^ (((r >> 1) & 3) << 4));
  }

  for (int k0 = 0; k0 < K; k0 += 32) {
#pragma unroll
    for (int i = 0; i < 2; ++i) {
      int p = pb0 + i * 4096;
      gll16(A + (size_t)(m0 + srow[i]) * K + k0 + scol[i], (u16*)((char*)sA + p));
      gll16(B + (size_t)(n0 + srow[i]) * K + k0 + scol[i], (u16*)((char*)sB + p));
    }
    __syncthreads();
    bf16x8 af[4], bfr[4];
#pragma unroll
    for (int m = 0; m < 4; ++m) af[m] = *(const bf16x8*)((const char*)sA + aoff[m]);
#pragma unroll
    for (int n = 0; n < 4; ++n) bfr[n] = *(const bf16x8*)((const char*)sB + boff[n]);
#pragma unroll
    for (int m = 0; m < 4; ++m)
#pragma unroll
      for (int n = 0; n < 4; ++n)
        acc[m][n] = __builtin_amdgcn_mfma_f32_16x16x32_bf16(af[m], bfr[n], acc[m][n], 0, 0, 0);
    __syncthreads();
  }

#pragma unroll
  for (int m = 0; m < 4; ++m)
#pragma unroll
    for (int i = 0; i < 4; ++i) {
      int gr = m0 + wm + m * 16 + (lane >> 4) * 4 + i;
      float* crow = C + (size_t)gr * N + n0 + wn + l15;
#pragma unroll
      for (int n = 0; n < 4; ++n) crow[n * 16] = acc[m][n][i];
    }
}

// ---------------- RMSNorm + RoPE + V cast + gate ----------------
#define QSCALE 0.18033688011112042f
__global__ __launch_bounds__(256) void norm_rope_gate(const float* __restrict__ qkv, const float* __restrict__ x,
                                                      const float* __restrict__ qw, const float* __restrict__ kw,
                                                      const float* __restrict__ gw,
                                                      u16* __restrict__ Q, u16* __restrict__ Kd,
                                                      u16* __restrict__ V, float* __restrict__ gate) {
  const int t = blockIdx.x * 4 + (threadIdx.x >> 6);
  const int lane = threadIdx.x & 63;
  const int b = t >> 11, s = t & 2047;
  const float* base = qkv + (size_t)t * 1536;
  const int ri = lane >> 1;
  float sn, cs;
  sincosf((float)s * expf(-(float)ri * (9.21034037198f / 32.0f)), &sn, &cs);
  const float qwl = qw[lane], kwl = kw[lane];

  for (int hh = 0; hh < 16; ++hh) {
    float v = base[hh * 64 + lane];
    float ss = v * v;
#pragma unroll
    for (int off = 32; off >= 1; off >>= 1) ss += __shfl_xor(ss, off);
    float r = rsqrtf(ss * (1.0f / 64.0f) + 1.1920929e-7f);
    float xn = v * r * qwl;
    float p = __shfl_xor(xn, 1);
    float outv = ((lane & 1) == 0) ? (xn * cs - p * sn) : (xn * cs + p * sn);
    Q[((size_t)(b * 16 + hh) * 2048 + s) * 64 + lane] = f2bf(outv * QSCALE);
  }
  for (int hh = 0; hh < 4; ++hh) {
    float v = base[1024 + hh * 64 + lane];
    float ss = v * v;
#pragma unroll
    for (int off = 32; off >= 1; off >>= 1) ss += __shfl_xor(ss, off);
    float r = rsqrtf(ss * (1.0f / 64.0f) + 1.1920929e-7f);
    float xn = v * r * kwl;
    float p = __shfl_xor(xn, 1);
    float outv = ((lane & 1) == 0) ? (xn * cs - p * sn) : (xn * cs + p * sn);
    Kd[((size_t)(b * 4 + hh) * 2048 + s) * 64 + lane] = f2bf(outv);
    V[((size_t)(b * 4 + hh) * 2048 + s) * 64 + lane] = f2bf(base[1280 + hh * 64 + lane]);
  }
  if (lane < 16) {
    float g = 0.f;
#pragma unroll
    for (int j = 0; j < 12; ++j) g += x[(size_t)t * 1024 + j] * gw[lane * 12 + j];
    gate[(size_t)t * 16 + lane] = 1.0f / (1.0f + __expf(-g));
  }
}

// ---------------- V transpose: [bh][s][d] -> [bh][d][s] ----------------
__global__ __launch_bounds__(256) void transpose_v64(const u16* __restrict__ V, u16* __restrict__ Vt) {
  __shared__ __align__(16) u16 tile[64][72];
  const int st = blockIdx.x, bh = blockIdx.y;
  const u16* src = V + ((size_t)bh * 2048 + st * 64) * 64;
  u16* dst = Vt + (size_t)bh * 64 * 2048 + st * 64;
  const int t = threadIdx.x;
  const int r = t >> 2, c0 = (t & 3) * 16;
#pragma unroll
  for (int j = 0; j < 2; ++j)
    *(u16x8*)&tile[r][c0 + j * 8] = *(const u16x8*)&src[(size_t)r * 64 + c0 + j * 8];
  __syncthreads();
  u16 tmp[16];
#pragma unroll
  for (int j = 0; j < 16; ++j) tmp[j] = tile[c0 + j][r];
#pragma unroll
  for (int j = 0; j < 2; ++j)
    *(u16x8*)&dst[(size_t)r * 2048 + c0 + j * 8] = *(const u16x8*)&tmp[j * 8];
}

// ---------------- Flash attention: paired q-tiles + KV-parity split, swapped QK^T ------
// grid (16, B*H, 2). LDS = 40960 B exactly -> 4 blocks/CU (the full 4-blocks/CU grid
// becomes co-resident). sK/sV/sP are LINEAR with T2 XOR swizzle (byte ^= (row&7)<<4),
// applied identically on write and read (reg-staged both sides).
__global__ __launch_bounds__(256) void attn_fwd_pair(const u16* __restrict__ Q, const u16* __restrict__ Kg,
                                                     const u16* __restrict__ Vt,
                                                     u16* __restrict__ accP, float* __restrict__ lP) {
  __shared__ __align__(16) u16 sK[2][64 * 64];  // K[kv][d], double-buffered, swizzled
  __shared__ __align__(16) u16 sV[2][64 * 64];  // Vt[d][kv], swizzled
  __shared__ __align__(16) u16 sP[4][16 * 64];  // per-wave P[q][kv], swizzled

  const int tid = threadIdx.x;
  const int w = tid >> 6, lane = tid & 63;
  const int l15 = lane & 15, lg = lane >> 4;
  const int qiA = blockIdx.x;          // 0..15
  const int qiB = 31 - qiA;            // 31..16
  const int z = blockIdx.z;
  const int bh = blockIdx.y, b = bh >> 4, h = bh & 15, kvh = h >> 2;

  const u16* Qp = Q + (size_t)(b * 16 + h) * 2048 * 64;
  const u16* Kp = Kg + (size_t)(b * 4 + kvh) * 2048 * 64;
  const u16* Vp = Vt + (size_t)(b * 4 + kvh) * 64 * 2048;

  const int q0s[2] = {qiA * 64, qiB * 64};
  bf16x8 qa[2][2];
#pragma unroll
  for (int s = 0; s < 2; ++s) {
    const u16* qrow = Qp + (size_t)(q0s[s] + w * 16 + l15) * 64 + lg * 8;
    qa[s][0] = *(const bf16x8*)qrow;
    qa[s][1] = *(const bf16x8*)(qrow + 32);
  }

  f32x4 acc[2][4] = {};
  float l_s[2] = {0.f, 0.f};

  // staging addresses: global linear; LDS swizzled
  const int srw = tid >> 2;                       // 0..63 rows
  const int scb = (tid & 3) * 32;                 // byte col base in row (128 B rows)
  const int swzS = (srw & 7) << 4;
  const int st0 = srw * 128 + (scb ^ swzS);
  const int st1 = srw * 128 + ((scb + 16) ^ swzS);
  const u16* kgp = Kp + (size_t)srw * 64 + (tid & 3) * 16;
  const u16* vgp = Vp + (size_t)srw * 2048 + (tid & 3) * 16;

  // fragment read byte offsets (swizzle: row&7 == l15&7 for rows ct*16+l15)
  const int swzF = (l15 & 7) << 4;
  const int fo0 = (lg * 16) ^ swzF;        // k-half 0
  const int fo1 = (64 + lg * 16) ^ swzF;   // k-half 1

  // prologue: stage tile z into buffer 0
  u16x8 kr0 = *(const u16x8*)(kgp + (size_t)z * 64 * 64), kr1 = *(const u16x8*)(kgp + (size_t)z * 64 * 64 + 8);
  u16x8 vr0 = *(const u16x8*)(vgp + z * 64),              vr1 = *(const u16x8*)(vgp + z * 64 + 8);
  *(u16x8*)((char*)sK[0] + st0) = kr0; *(u16x8*)((char*)sK[0] + st1) = kr1;
  *(u16x8*)((char*)sV[0] + st0) = vr0; *(u16x8*)((char*)sV[0] + st1) = vr1;
  __syncthreads();

  for (int t = z; t <= qiB; t += 2) {
    const int buf = (t >> 1) & 1;

    // T14: issue tile t+2's global loads now; consume after compute.
    if (t + 2 <= qiB) {
      const u16* kg = kgp + (size_t)(t + 2) * 64 * 64;
      const u16* vg = vgp + (t + 2) * 64;
      kr0 = *(const u16x8*)kg; kr1 = *(const u16x8*)(kg + 8);
      vr0 = *(const u16x8*)vg; vr1 = *(const u16x8*)(vg + 8);
    }

    // shared K / V fragments (read once, used by both streams)
    bf16x8 kf[4][2], vf[4][2];
#pragma unroll
    for (int ct = 0; ct < 4; ++ct) {
      const char* krow = (const char*)sK[buf] + (ct * 16 + l15) * 128;
      const char* vrow = (const char*)sV[buf] + (ct * 16 + l15) * 128;
      kf[ct][0] = *(const bf16x8*)(krow + fo0);
      kf[ct][1] = *(const bf16x8*)(krow + fo1);
      vf[ct][0] = *(const bf16x8*)(vrow + fo0);
      vf[ct][1] = *(const bf16x8*)(vrow + fo1);
    }

#pragma unroll
    for (int s = 0; s < 2; ++s) {
      if (s == 0 && t > qiA) continue;     // stream A done (uniform branch)
      const int diag = s ? qiB : qiA;

      // S^T = K Q^T: lane holds S[kv=ct*16+lg*4+i][q=l15]
      f32x4 st[4];
#pragma unroll
      for (int ct = 0; ct < 4; ++ct) {
        f32x4 s4 = {};
        s4 = __builtin_amdgcn_mfma_f32_16x16x32_bf16(kf[ct][0], qa[s][0], s4, 0, 0, 0);
        s4 = __builtin_amdgcn_mfma_f32_16x16x32_bf16(kf[ct][1], qa[s][1], s4, 0, 0, 0);
        st[ct] = s4;
      }

      if (t == diag) {
        const int ql = w * 16 + l15;
#pragma unroll
        for (int ct = 0; ct < 4; ++ct)
#pragma unroll
          for (int i = 0; i < 4; ++i)
            st[ct][i] = (ct * 16 + lg * 4 + i <= ql) ? st[ct][i] : -1e30f;
      }

      // P = exp2(S'), pack pairs, accumulate per-lane row-sum (q=l15)
      float ls = 0.f;
      const int swzP = (l15 & 7) << 4;
      char* prow = (char*)sP[w] + l15 * 128;
#pragma unroll
      for (int ct = 0; ct < 4; ++ct) {
        float p0 = exp2f(st[ct][0]), p1 = exp2f(st[ct][1]);
        float p2 = exp2f(st[ct][2]), p3 = exp2f(st[ct][3]);
        ls += (p0 + p1) + (p2 + p3);
        u32 lo = (u32)f2bfh(p0) | ((u32)f2bfh(p1) << 16);
        u32 hi = (u32)f2bfh(p2) | ((u32)f2bfh(p3) << 16);
        *(u32x2*)(prow + ((ct * 32 + lg * 8) ^ swzP)) = (u32x2){lo, hi};
      }
      l_s[s] += ls;

      // read P as A-fragments (wave-internal; compiler-ordered lgkmcnt); 16B aligned
      bf16x8 pa0 = *(const bf16x8*)(prow + ((lg * 16) ^ swzP));
      bf16x8 pa1 = *(const bf16x8*)(prow + ((64 + lg * 16) ^ swzP));

#pragma unroll
      for (int n = 0; n < 4; ++n) {
        acc[s][n] = __builtin_amdgcn_mfma_f32_16x16x32_bf16(pa0, vf[n][0], acc[s][n], 0, 0, 0);
        acc[s][n] = __builtin_amdgcn_mfma_f32_16x16x32_bf16(pa1, vf[n][1], acc[s][n], 0, 0, 0);
      }
    }

    if (t + 2 <= qiB) {
      *(u16x8*)((char*)sK[buf ^ 1] + st0) = kr0; *(u16x8*)((char*)sK[buf ^ 1] + st1) = kr1;
      *(u16x8*)((char*)sV[buf ^ 1] + st0) = vr0; *(u16x8*)((char*)sV[buf ^ 1] + st1) = vr1;
    }
    __syncthreads();
  }

  // epilogue: reduce l across lg-groups (lanes l15, l15+16, +32, +48), write partials.
#pragma unroll
  for (int s = 0; s < 2; ++s) {
    float lv = l_s[s];
    lv += __shfl_xor(lv, 16);
    lv += __shfl_xor(lv, 32);
    if (lg == 0) {
      int qrow = q0s[s] + w * 16 + l15;
      lP[((size_t)z * 4096 + b * 2048 + qrow) * 16 + h] = lv;
    }
#pragma unroll
    for (int i = 0; i < 4; ++i) {
      int srowg = q0s[s] + w * 16 + lg * 4 + i;
      size_t rowbase = (size_t)z * 4096 + b * 2048 + srowg;
      u16* orow = accP + rowbase * 1024 + h * 64 + l15;
#pragma unroll
      for (int n = 0; n < 4; ++n) orow[n * 16] = f2bfh(acc[s][n][i]);
    }
  }
}

// ---------------- combine KV-split partials: O = (a0+a1)/(l0+l1) * gate ----------------
__global__ __launch_bounds__(256) void attn_combine(const u16* __restrict__ accP, const float* __restrict__ lP,
                                                    const float* __restrict__ gate, u16* __restrict__ attnh) {
  const size_t e = ((size_t)blockIdx.x * 256 + threadIdx.x) * 8;
  const int token = (int)(e >> 10);
  const int h = (int)((e >> 6) & 15);
  u16x8 a0 = *(const u16x8*)(accP + e);
  u16x8 a1 = *(const u16x8*)(accP + ((size_t)4096 << 10) + e);
  float l0 = lP[(size_t)token * 16 + h];
  float l1 = lP[(size_t)4096 * 16 + (size_t)token * 16 + h];
  float g = gate[(size_t)token * 16 + h] / (l0 + l1);
  u16x8 o;
#pragma unroll
  for (int j = 0; j < 8; ++j) o[j] = f2bfh((bf2f(a0[j]) + bf2f(a1[j])) * g);
  *(u16x8*)(attnh + e) = o;
}

// ---------------- launch ----------------
extern "C" void kernel_launch(void* const* d_in, const int* in_sizes, int n_in,
                              void* d_out, int out_size, void* d_ws, size_t ws_size,
                              hipStream_t stream) {
  const float* x  = (const float*)d_in[0];
  const float* Wf = (const float*)d_in[1];
  const float* qw = (const float*)d_in[2];
  const float* kw = (const float*)d_in[3];
  const float* gw = (const float*)d_in[4];
  float* out = (float*)d_out;

  char* ws = (char*)d_ws;
  size_t off = 0;
  auto alloc = [&](size_t bytes) { void* p = ws + off; off += (bytes + 255) & ~(size_t)255; return p; };

  u16*   xb   = (u16*)alloc((size_t)4096 * 1024 * 2);
  u16*   wb   = (u16*)alloc((size_t)2560 * 1024 * 2);
  float* qkv  = (float*)alloc((size_t)4096 * 1536 * 4);
  u16*   Qb   = (u16*)alloc((size_t)2 * 16 * 2048 * 64 * 2);
  u16*   Kb   = (u16*)alloc((size_t)2 * 4 * 2048 * 64 * 2);
  u16*   Vb   = (u16*)alloc((size_t)2 * 4 * 2048 * 64 * 2);
  u16*   Vtb  = (u16*)alloc((size_t)2 * 4 * 2048 * 64 * 2);
  float* gate = (float*)alloc((size_t)2 * 2048 * 16 * 4);
  float* lP   = (float*)alloc((size_t)2 * 4096 * 16 * 4);
  // partial acc (16 MB) aliases qkv (24 MB, dead after norm_rope_gate);
  // attnh (8 MB) aliases xb (dead after the QKV GEMM).
  u16* accP  = (u16*)qkv;
  u16* attnh = xb;

  cvt2_bf16<<<dim3(6656), dim3(256), 0, stream>>>(x, xb, 4096 * 1024 / 4, Wf, wb, 2560 * 1024 / 4);
  gemm_nt<<<dim3(32, 12), dim3(256), 0, stream>>>(xb, wb, qkv, 4096, 1536, 1024);
  norm_rope_gate<<<dim3(1024), dim3(256), 0, stream>>>(qkv, x, qw, kw, gw, Qb, Kb, Vb, gate);
  transpose_v64<<<dim3(32, 8), dim3(256), 0, stream>>>(Vb, Vtb);
  attn_fwd_pair<<<dim3(16, 32, 2), dim3(256), 0, stream>>>(Qb, Kb, Vtb, accP, lP);
  attn_combine<<<dim3(2048), dim3(256), 0, stream>>>(accP, lP, gate, attnh);
  gemm_nt<<<dim3(32, 8), dim3(256), 0, stream>>>(attnh, wb + (size_t)1536 * 1024, out, 4096, 1024, 1024);
}